// Round 9
// baseline (3239.028 us; speedup 1.0000x reference)
//
#include <hip/hip_runtime.h>

typedef unsigned short ushort;
typedef __attribute__((ext_vector_type(8))) short short8;
typedef __attribute__((ext_vector_type(4))) float f32x4;

// Problem constants
constexpr int Bn = 8, Tn = 16, Nn = 512, Cn = 64, Hn = 64, En = 16384, Ln = 2;
constexpr int NC = Nn * Cn;           // 32768
constexpr int MROWS = Bn * Nn;        // 4096

// ---------------- workspace layout (in floats) ----------------
constexpr size_t OFF_DEG  = 0;
constexpr size_t OFF_DINV = 512;
constexpr size_t OFF_L1D  = 1024;                         // 512*512
constexpr size_t OFF_L2D  = OFF_L1D + 262144;
constexpr size_t OFF_WZR  = OFF_L2D + 262144;             // 2*384*128
constexpr size_t OFF_WHT  = OFF_WZR + 2*384*128;          // 2*384*64
constexpr size_t OFF_BZR  = OFF_WHT + 2*384*64;
constexpr size_t OFF_BHT  = OFF_BZR + 256;
constexpr size_t OFF_W1C  = OFF_BHT + 128;                // 8192
constexpr size_t OFF_T1X  = OFF_W1C + 8192;               // B*T*N*C
constexpr size_t OFF_T2X  = OFF_T1X + (size_t)Bn*Tn*NC;
constexpr size_t OFF_H    = OFF_T2X + (size_t)Bn*Tn*NC;   // B*N*H
constexpr size_t OFF_Z    = OFF_H   + (size_t)Bn*NC;
constexpr size_t OFF_HR   = OFF_Z   + (size_t)Bn*NC;
constexpr size_t OFF_SP   = OFF_HR  + (size_t)Bn*NC;      // sproj; W-frags alias this
constexpr size_t OFF_TP   = OFF_SP  + (size_t)MROWS*Hn;   //   (recurrence-only lifetime)
constexpr size_t OFF_LFH  = OFF_TP  + (size_t)MROWS*Hn;   // L-frags bf16 hi/lo
constexpr size_t OFF_LFL  = OFF_LFH + 262144;
constexpr size_t OFF_HTH  = OFF_LFL + 262144;             // transposed bf16 h/hr hi/lo
constexpr size_t OFF_HTL  = OFF_HTH + 131072;
constexpr size_t OFF_HRTH = OFF_HTL + 131072;
constexpr size_t OFF_HRTL = OFF_HRTH + 131072;
constexpr size_t OFF_END  = OFF_HRTL + 131072;

__device__ __forceinline__ ushort f2bf(float f) {
    unsigned u = __float_as_uint(f);
    u = u + 0x7FFF + ((u >> 16) & 1);
    return (ushort)(u >> 16);
}
__device__ __forceinline__ float bf2f(ushort h) {
    return __uint_as_float(((unsigned)h) << 16);
}
// fragment-linear LDS layout for a 16x64 bf16 A-operand panel:
// value (m,k) lives at (k>>5)*512 + ((k>>3)&3)*128 + m*8 + (k&7)
__device__ __forceinline__ int fragaddr(int m, int k) {
    return ((k >> 5) << 9) + (((k >> 3) & 3) << 7) + (m << 3) + (k & 7);
}

#define MFMA16(a, b, c) __builtin_amdgcn_mfma_f32_16x16x32_bf16((a), (b), (c), 0, 0, 0)

// ---------------- setup kernels ----------------
__global__ void k_deg(const float* __restrict__ w, const int* __restrict__ src,
                      float* __restrict__ deg) {
    int e = blockIdx.x * 256 + threadIdx.x;
    if (e < En) atomicAdd(&deg[src[e]], w[e]);
}

__global__ void k_dinv(const float* __restrict__ deg, float* __restrict__ dinv) {
    int n = blockIdx.x * 256 + threadIdx.x;
    if (n < Nn) {
        float d = deg[n];
        dinv[n] = d > 0.f ? rsqrtf(fmaxf(d, 1e-12f)) : 0.f;
    }
}

__global__ void k_nwdense(const float* __restrict__ w, const int* __restrict__ src,
                          const int* __restrict__ dst, const float* __restrict__ dinv,
                          float* __restrict__ L1d) {
    int e = blockIdx.x * 256 + threadIdx.x;
    if (e < En) {
        int s = src[e], d = dst[e];
        float nw = -w[e] * dinv[s] * dinv[d];
        atomicAdd(&L1d[d * Nn + s], nw);
    }
}

// L2 = 2*(L1@L1) - I
__global__ __launch_bounds__(256) void k_l2(const float* __restrict__ A,
                                            float* __restrict__ C) {
    __shared__ float As[64][33];
    __shared__ float Bs[32][65];
    int t = threadIdx.x;
    int i0 = (blockIdx.x >> 3) * 64;
    int j0 = (blockIdx.x & 7) * 64;
    int tx = t & 15, ty = t >> 4;
    float acc[4][4] = {};
    int ar = t >> 2, ac = (t & 3) * 8;
    int br = t >> 3, bc = (t & 7) * 8;
    for (int kc = 0; kc < 512; kc += 32) {
        float4 a0 = *(const float4*)&A[(size_t)(i0 + ar) * 512 + kc + ac];
        float4 a1 = *(const float4*)&A[(size_t)(i0 + ar) * 512 + kc + ac + 4];
        float4 b0 = *(const float4*)&A[(size_t)(kc + br) * 512 + j0 + bc];
        float4 b1 = *(const float4*)&A[(size_t)(kc + br) * 512 + j0 + bc + 4];
        As[ar][ac+0]=a0.x; As[ar][ac+1]=a0.y; As[ar][ac+2]=a0.z; As[ar][ac+3]=a0.w;
        As[ar][ac+4]=a1.x; As[ar][ac+5]=a1.y; As[ar][ac+6]=a1.z; As[ar][ac+7]=a1.w;
        Bs[br][bc+0]=b0.x; Bs[br][bc+1]=b0.y; Bs[br][bc+2]=b0.z; Bs[br][bc+3]=b0.w;
        Bs[br][bc+4]=b1.x; Bs[br][bc+5]=b1.y; Bs[br][bc+6]=b1.z; Bs[br][bc+7]=b1.w;
        __syncthreads();
#pragma unroll 8
        for (int kk = 0; kk < 32; kk++) {
            float av[4], bv[4];
#pragma unroll
            for (int r = 0; r < 4; r++) av[r] = As[ty * 4 + r][kk];
#pragma unroll
            for (int c = 0; c < 4; c++) bv[c] = Bs[kk][tx * 4 + c];
#pragma unroll
            for (int r = 0; r < 4; r++)
#pragma unroll
                for (int c = 0; c < 4; c++) acc[r][c] += av[r] * bv[c];
        }
        __syncthreads();
    }
#pragma unroll
    for (int r = 0; r < 4; r++)
#pragma unroll
        for (int c = 0; c < 4; c++) {
            int i = i0 + ty * 4 + r, j = j0 + tx * 4 + c;
            C[(size_t)i * 512 + j] = 2.f * acc[r][c] - (i == j ? 1.f : 0.f);
        }
}

// L1/L2 -> bf16 split A-fragments; idx = ((mat*32+rb)*16 + kc)*512 + lane*8 + j
__global__ void k_lfrag(const float* __restrict__ L1, const float* __restrict__ L2,
                        ushort* __restrict__ AfH, ushort* __restrict__ AfL) {
    int idx = blockIdx.x * 256 + threadIdx.x;   // 0..524287
    int j = idx & 7;
    int lane = (idx >> 3) & 63;
    int kc = (idx >> 9) & 15;
    int rb = (idx >> 13) & 31;
    int mat = idx >> 18;
    int row = rb * 16 + (lane & 15);
    int k = kc * 32 + (lane >> 4) * 8 + j;
    float v = (mat ? L2 : L1)[(size_t)row * 512 + k];
    ushort hi = f2bf(v);
    AfH[idx] = hi;
    AfL[idx] = f2bf(v - bf2f(hi));
}

// Wzr/Wht -> bf16 split B-fragments: idx = ((l*CT + ct)*12 + kc)*512 + lane*8 + j
__global__ void k_wfrag(const float* __restrict__ WzrC, const float* __restrict__ WhC,
                        ushort* __restrict__ WzFH, ushort* __restrict__ WzFL,
                        ushort* __restrict__ WhFH, ushort* __restrict__ WhFL) {
    int idx = blockIdx.x * 256 + threadIdx.x;
    if (idx < 98304) {
        int l = idx / 49152, off = idx % 49152;
        int tile = off >> 9, r = off & 511;
        int lane = r >> 3, j = r & 7;
        int ct = tile / 12, kc = tile % 12;
        int k = kc * 32 + (lane >> 4) * 8 + j;
        int n = ct * 16 + (lane & 15);
        float v = WzrC[(size_t)l * 49152 + k * 128 + n];
        ushort hi = f2bf(v);
        WzFH[idx] = hi;
        WzFL[idx] = f2bf(v - bf2f(hi));
    } else if (idx < 147456) {
        int t2 = idx - 98304;
        int l = t2 / 24576, off = t2 % 24576;
        int tile = off >> 9, r = off & 511;
        int lane = r >> 3, j = r & 7;
        int ct = tile / 12, kc = tile % 12;
        int k = kc * 32 + (lane >> 4) * 8 + j;
        int n = ct * 16 + (lane & 15);
        float v = WhC[(size_t)l * 24576 + k * 64 + n];
        ushort hi = f2bf(v);
        WhFH[t2] = hi;
        WhFL[t2] = f2bf(v - bf2f(hi));
    }
}

// ---------------- MFMA T1x/T2x: o1 = L1@x, o2 = L2@x per slice ----------------
// 512 blocks = 128 slices x 4 rowgroups(128 rows); B (x-chunk) double-buffered in LDS.
__global__ __launch_bounds__(256) void k_lxm(
        const ushort* __restrict__ AfH, const ushort* __restrict__ AfL,
        const float* __restrict__ in, float* __restrict__ o1, float* __restrict__ o2) {
    __shared__ ushort Bh[2][2176];   // [buf][n*34 + k]  (pad 34 halves)
    __shared__ ushort Bl[2][2176];
    int slice = blockIdx.x >> 2;
    int rg = blockIdx.x & 3;
    const float* xs = in + (size_t)slice * NC;
    int tid = threadIdx.x;
    int lane = tid & 63, wav = tid >> 6;
    int quad = lane >> 4, l15 = lane & 15;
    int sn = tid & 63, skq = tid >> 6;
    int rta = rg * 8 + wav * 2;
    size_t ab[2][2];   // [rt][mat]
    ab[0][0] = ((size_t)(rta + 0) * 16) * 512 + lane * 8;
    ab[1][0] = ((size_t)(rta + 1) * 16) * 512 + lane * 8;
    ab[0][1] = ((size_t)(32 + rta + 0) * 16) * 512 + lane * 8;
    ab[1][1] = ((size_t)(32 + rta + 1) * 16) * 512 + lane * 8;
    f32x4 acc[2][2][4];
#pragma unroll
    for (int r = 0; r < 2; r++)
#pragma unroll
        for (int m = 0; m < 2; m++)
#pragma unroll
            for (int n = 0; n < 4; n++) acc[r][m][n] = (f32x4){0.f, 0.f, 0.f, 0.f};

    // stage chunk 0 into buf 0
    {
        float sv[8];
#pragma unroll
        for (int i = 0; i < 8; i++) sv[i] = xs[(size_t)(skq * 8 + i) * 64 + sn];
        short8 hi8, lo8;
#pragma unroll
        for (int i = 0; i < 8; i++) {
            ushort hv = f2bf(sv[i]);
            hi8[i] = (short)hv;
            lo8[i] = (short)f2bf(sv[i] - bf2f(hv));
        }
        *(short8*)&Bh[0][sn * 34 + skq * 8] = hi8;
        *(short8*)&Bl[0][sn * 34 + skq * 8] = lo8;
    }
    // A prefetch slots [2]
    short8 pah[2][2][2], pal[2][2][2];  // [slot][rt][mat]
#pragma unroll
    for (int s = 0; s < 2; s++)
#pragma unroll
        for (int r = 0; r < 2; r++)
#pragma unroll
            for (int m = 0; m < 2; m++) {
                pah[s][r][m] = *(const short8*)&AfH[ab[r][m] + (size_t)s * 512];
                pal[s][r][m] = *(const short8*)&AfL[ab[r][m] + (size_t)s * 512];
            }
    __syncthreads();
    for (int kc = 0; kc < 16; kc++) {
        int cur = kc & 1;
        float sv[8];
        if (kc < 15) {
#pragma unroll
            for (int i = 0; i < 8; i++)
                sv[i] = xs[(size_t)((kc + 1) * 32 + skq * 8 + i) * 64 + sn];
        }
#pragma unroll
        for (int nt = 0; nt < 4; nt++) {
            short8 bh8 = *(const short8*)&Bh[cur][(nt * 16 + l15) * 34 + quad * 8];
            short8 bl8 = *(const short8*)&Bl[cur][(nt * 16 + l15) * 34 + quad * 8];
#pragma unroll
            for (int r = 0; r < 2; r++)
#pragma unroll
                for (int m = 0; m < 2; m++) {
                    acc[r][m][nt] = MFMA16(pah[cur][r][m], bh8, acc[r][m][nt]);
                    acc[r][m][nt] = MFMA16(pah[cur][r][m], bl8, acc[r][m][nt]);
                    acc[r][m][nt] = MFMA16(pal[cur][r][m], bh8, acc[r][m][nt]);
                }
        }
        if (kc + 2 < 16) {
            size_t o = (size_t)(kc + 2) * 512;
#pragma unroll
            for (int r = 0; r < 2; r++)
#pragma unroll
                for (int m = 0; m < 2; m++) {
                    pah[cur][r][m] = *(const short8*)&AfH[ab[r][m] + o];
                    pal[cur][r][m] = *(const short8*)&AfL[ab[r][m] + o];
                }
        }
        if (kc < 15) {
            short8 hi8, lo8;
#pragma unroll
            for (int i = 0; i < 8; i++) {
                ushort hv = f2bf(sv[i]);
                hi8[i] = (short)hv;
                lo8[i] = (short)f2bf(sv[i] - bf2f(hv));
            }
            *(short8*)&Bh[cur ^ 1][sn * 34 + skq * 8] = hi8;
            *(short8*)&Bl[cur ^ 1][sn * 34 + skq * 8] = lo8;
        }
        __syncthreads();
    }
    float* os1 = o1 + (size_t)slice * NC;
    float* os2 = o2 + (size_t)slice * NC;
#pragma unroll
    for (int r = 0; r < 2; r++)
#pragma unroll
        for (int nt = 0; nt < 4; nt++)
#pragma unroll
            for (int reg = 0; reg < 4; reg++) {
                size_t row = (size_t)((rta + r) * 16 + quad * 4 + reg);
                os1[row * 64 + nt * 16 + l15] = acc[r][0][nt][reg];
                os2[row * 64 + nt * 16 + l15] = acc[r][1][nt][reg];
            }
}

// repack weights
__global__ void k_repack(const float* __restrict__ Wx, const float* __restrict__ bx,
                         const float* __restrict__ Wh, const float* __restrict__ bh,
                         const float* __restrict__ W1,
                         float* __restrict__ WzrC, float* __restrict__ WhC,
                         float* __restrict__ bzr, float* __restrict__ bht,
                         float* __restrict__ W1cat) {
    int idx = blockIdx.x * 256 + threadIdx.x;
    if (idx < 98304) {
        int l = idx / 49152, r = idx % 49152;
        int k = r / 128, j = r % 128;
        int g = j >> 6, hh = j & 63;
        int kc, c; const float* s;
        if (k < 192) { kc = k / 64; c = k % 64; s = Wh; }
        else { kc = (k - 192) / 64; c = (k - 192) % 64; s = Wx; }
        WzrC[idx] = s[((((size_t)(l*3 + g))*3 + kc)*64 + c)*64 + hh];
    } else if (idx < 147456) {
        int tI = idx - 98304;
        int l = tI / 24576, r = tI % 24576;
        int k = r / 64, hh = r % 64;
        int kc, c; const float* s;
        if (k < 192) { kc = k / 64; c = k % 64; s = Wh; }
        else { kc = (k - 192) / 64; c = (k - 192) % 64; s = Wx; }
        WhC[tI] = s[((((size_t)(l*3 + 2))*3 + kc)*64 + c)*64 + hh];
    } else if (idx < 147712) {
        int tI = idx - 147456;
        int l = tI >> 7, j = tI & 127;
        int g = j >> 6, hh = j & 63;
        bzr[tI] = bh[(l*3 + g)*64 + hh] + bx[(l*3 + g)*64 + hh];
    } else if (idx < 147840) {
        int tI = idx - 147712;
        int l = tI >> 6, hh = tI & 63;
        bht[tI] = bh[(l*3 + 2)*64 + hh] + bx[(l*3 + 2)*64 + hh];
    } else if (idx < 156032) {
        int tI = idx - 147840;
        int c = tI >> 7, j = tI & 127;
        W1cat[tI] = (j < 64) ? W1[c*64 + j] : W1[(64 + c)*64 + (j - 64)];
    }
}

// ================= full-MFMA cell kernels: 256 blocks x 16 rows =================
// LDS (floats): AH@0 (6x1024 halves = 3072 fl) | AL@3072 | PRED@6144 (2048) | HRS@8192 (1024)

// common: stage segs 0,3,4,5 (fp32 global -> bf16 hi/lo frags)
__device__ __forceinline__ void stage_segs(
        ushort* AH, ushort* AL, const float* s0, const float* x,
        const float* t1x, const float* t2x, size_t xoff, int tid) {
    int p = tid * 4;
    int m = p >> 6, kb = p & 63;
    int fa = fragaddr(m, kb);
    const float* srcs[4] = { s0, x + xoff, t1x + xoff, t2x + xoff };
    const int sidx[4] = { 0, 3, 4, 5 };
#pragma unroll
    for (int q = 0; q < 4; q++) {
        float4 v = *(const float4*)&srcs[q][(size_t)m * 64 + kb];
        float vv[4] = { v.x, v.y, v.z, v.w };
        int base = sidx[q] * 1024 + fa;
#pragma unroll
        for (int j = 0; j < 4; j++) {
            ushort hi = f2bf(vv[j]);
            AH[base + j] = hi;
            AL[base + j] = f2bf(vv[j] - bf2f(hi));
        }
    }
}

// phase A: U1 = L1[rows,:]@src, U2 = L2[rows,:]@src via split-bf16 MFMA.
// Depth-4 prefetch; 6 independent accumulators (no dependent MFMA chains).
__device__ __forceinline__ void phase_A16(
        ushort* AH, ushort* AL,
        const ushort* __restrict__ sTh, const ushort* __restrict__ sTl,
        const ushort* __restrict__ AfH, const ushort* __restrict__ AfL,
        int rowblk, int tid) {
    int lane = tid & 63, wav = tid >> 6;
    int quad = lane >> 4, l15 = lane & 15;
    size_t ab1 = ((size_t)rowblk * 16) * 512 + lane * 8;
    size_t ab2 = ((size_t)(32 + rowblk) * 16) * 512 + lane * 8;
    size_t bb = (size_t)(wav * 16 + l15) * 512 + quad * 8;
    f32x4 p1a = {0.f,0.f,0.f,0.f}, p1b = p1a, p1c = p1a;
    f32x4 p2a = p1a, p2b = p1a, p2c = p1a;
    short8 a1h[4], a1l[4], a2h[4], a2l[4], bh[4], bl[4];
#pragma unroll
    for (int s = 0; s < 4; s++) {
        size_t o = (size_t)s * 512;
        a1h[s] = *(const short8*)&AfH[ab1 + o];
        a1l[s] = *(const short8*)&AfL[ab1 + o];
        a2h[s] = *(const short8*)&AfH[ab2 + o];
        a2l[s] = *(const short8*)&AfL[ab2 + o];
        bh[s]  = *(const short8*)&sTh[bb + s * 32];
        bl[s]  = *(const short8*)&sTl[bb + s * 32];
    }
#pragma unroll
    for (int kc = 0; kc < 16; kc++) {
        int s = kc & 3;
        p1a = MFMA16(a1h[s], bh[s], p1a);
        p1b = MFMA16(a1h[s], bl[s], p1b);
        p1c = MFMA16(a1l[s], bh[s], p1c);
        p2a = MFMA16(a2h[s], bh[s], p2a);
        p2b = MFMA16(a2h[s], bl[s], p2b);
        p2c = MFMA16(a2l[s], bh[s], p2c);
        if (kc + 4 < 16) {
            size_t o = (size_t)(kc + 4) * 512;
            a1h[s] = *(const short8*)&AfH[ab1 + o];
            a1l[s] = *(const short8*)&AfL[ab1 + o];
            a2h[s] = *(const short8*)&AfH[ab2 + o];
            a2l[s] = *(const short8*)&AfL[ab2 + o];
            bh[s]  = *(const short8*)&sTh[bb + (kc + 4) * 32];
            bl[s]  = *(const short8*)&sTl[bb + (kc + 4) * 32];
        }
    }
    int colA = wav * 16 + l15;
#pragma unroll
    for (int reg = 0; reg < 4; reg++) {
        int row = quad * 4 + reg;
        float u1 = p1a[reg] + p1b[reg] + p1c[reg];
        float u2 = p2a[reg] + p2b[reg] + p2c[reg];
        ushort h1 = f2bf(u1), h2 = f2bf(u2);
        int fa1 = 1024 + fragaddr(row, colA);
        int fa2 = 2048 + fragaddr(row, colA);
        AH[fa1] = h1; AL[fa1] = f2bf(u1 - bf2f(h1));
        AH[fa2] = h2; AL[fa2] = f2bf(u2 - bf2f(h2));
    }
}

// stage1: z,r = sigmoid(A@Wzr + b); z->global; hr = h*r -> global fp32 + bf16 transposed
__global__ __launch_bounds__(256) void k_cell1(
        const float* __restrict__ h, const float* __restrict__ x,
        const float* __restrict__ t1x, const float* __restrict__ t2x,
        const ushort* __restrict__ AfH, const ushort* __restrict__ AfL,
        const ushort* __restrict__ hTh, const ushort* __restrict__ hTl,
        const ushort* __restrict__ WFH, const ushort* __restrict__ WFL,
        const float* __restrict__ bias,
        float* __restrict__ z, float* __restrict__ hr,
        ushort* __restrict__ hrTh, ushort* __restrict__ hrTl, int t) {
    __shared__ float lds[9216];
    ushort* AH = (ushort*)lds;
    ushort* AL = (ushort*)(lds + 3072);
    float* PRED = lds + 6144;
    float* HRS  = lds + 8192;
    int tid = threadIdx.x;
    int b = blockIdx.x >> 5;
    int rowblk = blockIdx.x & 31;
    int n0 = rowblk * 16;
    size_t hoff = ((size_t)b * Nn + n0) * 64;
    size_t xoff = ((size_t)(b * Tn + t) * Nn + n0) * 64;

    stage_segs(AH, AL, h + hoff, x, t1x, t2x, xoff, tid);
    phase_A16(AH, AL, hTh + (size_t)b * 32768, hTl + (size_t)b * 32768,
              AfH, AfL, rowblk, tid);
    __syncthreads();

    // phase B1: zr[16][128] = A[16][384] @ Wzr — depth-4 W / depth-2 A, split accs
    int lane = tid & 63, wav = tid >> 6;
    int quad = lane >> 4, l15 = lane & 15;
    {
        int abase = quad * 128 + l15 * 8;
        size_t w0 = ((size_t)wav * 12) * 512 + lane * 8;
        size_t w1 = ((size_t)(4 + wav) * 12) * 512 + lane * 8;
        f32x4 q0a = {0.f,0.f,0.f,0.f}, q0b = q0a, q0c = q0a;
        f32x4 q1a = q0a, q1b = q0a, q1c = q0a;
        short8 ah[2], al[2], w0h[4], w0l[4], w1h[4], w1l[4];
#pragma unroll
        for (int s = 0; s < 2; s++) {
            ah[s] = *(const short8*)&AH[abase + s * 512];
            al[s] = *(const short8*)&AL[abase + s * 512];
        }
#pragma unroll
        for (int s = 0; s < 4; s++) {
            size_t o = (size_t)s * 512;
            w0h[s] = *(const short8*)&WFH[w0 + o];
            w0l[s] = *(const short8*)&WFL[w0 + o];
            w1h[s] = *(const short8*)&WFH[w1 + o];
            w1l[s] = *(const short8*)&WFL[w1 + o];
        }
#pragma unroll
        for (int kt = 0; kt < 12; kt++) {
            int sa = kt & 1, sw = kt & 3;
            q0a = MFMA16(ah[sa], w0h[sw], q0a);
            q0b = MFMA16(ah[sa], w0l[sw], q0b);
            q0c = MFMA16(al[sa], w0h[sw], q0c);
            q1a = MFMA16(ah[sa], w1h[sw], q1a);
            q1b = MFMA16(ah[sa], w1l[sw], q1b);
            q1c = MFMA16(al[sa], w1h[sw], q1c);
            if (kt + 2 < 12) {
                ah[sa] = *(const short8*)&AH[abase + (kt + 2) * 512];
                al[sa] = *(const short8*)&AL[abase + (kt + 2) * 512];
            }
            if (kt + 4 < 12) {
                size_t o = (size_t)(kt + 4) * 512;
                w0h[sw] = *(const short8*)&WFH[w0 + o];
                w0l[sw] = *(const short8*)&WFL[w0 + o];
                w1h[sw] = *(const short8*)&WFH[w1 + o];
                w1l[sw] = *(const short8*)&WFL[w1 + o];
            }
        }
#pragma unroll
        for (int reg = 0; reg < 4; reg++) {
            int row = quad * 4 + reg;
            PRED[row * 128 + wav * 16 + l15] = q0a[reg] + q0b[reg] + q0c[reg];
            PRED[row * 128 + 64 + wav * 16 + l15] = q1a[reg] + q1b[reg] + q1c[reg];
        }
    }
    __syncthreads();
    for (int i = tid; i < 2048; i += 256) {
        int r = i >> 7, c = i & 127;
        float v = PRED[i] + bias[c];
        float s = 1.f / (1.f + __expf(-v));
        size_t grow = ((size_t)(b * Nn + n0 + r)) * 64;
        if (c < 64) {
            z[grow + c] = s;
        } else {
            int c2 = c - 64;
            int fa = fragaddr(r, c2);
            float hv = bf2f(AH[fa]) + bf2f(AL[fa]);
            float hrv = hv * s;
            hr[grow + c2] = hrv;
            HRS[r * 64 + c2] = hrv;
        }
    }
    __syncthreads();
    for (int i = tid; i < 1024; i += 256) {
        int c = i >> 4, r = i & 15;
        float hrv = HRS[r * 64 + c];
        size_t gi = (size_t)b * 32768 + (size_t)c * 512 + n0 + r;
        ushort hi = f2bf(hrv);
        hrTh[gi] = hi;
        hrTl[gi] = f2bf(hrv - bf2f(hi));
    }
}

// stage2: ht = tanh(A@Wht + b); h = z*h + (1-z)*ht -> global fp32 + bf16 transposed
__global__ __launch_bounds__(256) void k_cell2(
        const float* __restrict__ hrp, const float* __restrict__ x,
        const float* __restrict__ t1x, const float* __restrict__ t2x,
        const ushort* __restrict__ AfH, const ushort* __restrict__ AfL,
        const ushort* __restrict__ hrTh, const ushort* __restrict__ hrTl,
        const ushort* __restrict__ WFH, const ushort* __restrict__ WFL,
        const float* __restrict__ bias,
        const float* __restrict__ z, float* __restrict__ h,
        ushort* __restrict__ hTh, ushort* __restrict__ hTl, int t) {
    __shared__ float lds[9216];
    ushort* AH = (ushort*)lds;
    ushort* AL = (ushort*)(lds + 3072);
    float* PRED = lds + 6144;
    float* HRS  = lds + 8192;
    int tid = threadIdx.x;
    int b = blockIdx.x >> 5;
    int rowblk = blockIdx.x & 31;
    int n0 = rowblk * 16;
    size_t hoff = ((size_t)b * Nn + n0) * 64;
    size_t xoff = ((size_t)(b * Tn + t) * Nn + n0) * 64;

    stage_segs(AH, AL, hrp + hoff, x, t1x, t2x, xoff, tid);
    phase_A16(AH, AL, hrTh + (size_t)b * 32768, hrTl + (size_t)b * 32768,
              AfH, AfL, rowblk, tid);
    __syncthreads();

    // phase B2: ht[16][64] = A[16][384] @ Wht — depth-4 W / depth-2 A, split accs
    int lane = tid & 63, wav = tid >> 6;
    int quad = lane >> 4, l15 = lane & 15;
    {
        int abase = quad * 128 + l15 * 8;
        size_t w0 = ((size_t)wav * 12) * 512 + lane * 8;
        f32x4 qa = {0.f,0.f,0.f,0.f}, qb = qa, qc = qa;
        short8 ah[2], al[2], wh[4], wl[4];
#pragma unroll
        for (int s = 0; s < 2; s++) {
            ah[s] = *(const short8*)&AH[abase + s * 512];
            al[s] = *(const short8*)&AL[abase + s * 512];
        }
#pragma unroll
        for (int s = 0; s < 4; s++) {
            wh[s] = *(const short8*)&WFH[w0 + (size_t)s * 512];
            wl[s] = *(const short8*)&WFL[w0 + (size_t)s * 512];
        }
#pragma unroll
        for (int kt = 0; kt < 12; kt++) {
            int sa = kt & 1, sw = kt & 3;
            qa = MFMA16(ah[sa], wh[sw], qa);
            qb = MFMA16(ah[sa], wl[sw], qb);
            qc = MFMA16(al[sa], wh[sw], qc);
            if (kt + 2 < 12) {
                ah[sa] = *(const short8*)&AH[abase + (kt + 2) * 512];
                al[sa] = *(const short8*)&AL[abase + (kt + 2) * 512];
            }
            if (kt + 4 < 12) {
                size_t o = (size_t)(kt + 4) * 512;
                wh[sw] = *(const short8*)&WFH[w0 + o];
                wl[sw] = *(const short8*)&WFL[w0 + o];
            }
        }
#pragma unroll
        for (int reg = 0; reg < 4; reg++)
            PRED[(quad * 4 + reg) * 64 + wav * 16 + l15] = qa[reg] + qb[reg] + qc[reg];
    }
    __syncthreads();
    for (int i = tid; i < 1024; i += 256) {
        int c = i & 63;
        float ht = tanhf(PRED[i] + bias[c]);
        size_t p = ((size_t)(b * Nn + n0 + (i >> 6))) * 64 + c;
        float zz = z[p], hold = h[p];
        float hn = zz * hold + (1.f - zz) * ht;
        h[p] = hn;
        HRS[i] = hn;
    }
    __syncthreads();
    for (int i = tid; i < 1024; i += 256) {
        int c = i >> 4, r = i & 15;
        float hn = HRS[r * 64 + c];
        size_t gi = (size_t)b * 32768 + (size_t)c * 512 + n0 + r;
        ushort hi = f2bf(hn);
        hTh[gi] = hi;
        hTl[gi] = f2bf(hn - bf2f(hi));
    }
}

// ---------------- projections ----------------
__global__ __launch_bounds__(256) void k_proj(
        const float* __restrict__ h, const float* __restrict__ W1cat,
        const float* __restrict__ b1,
        float* __restrict__ sproj, float* __restrict__ tproj) {
    __shared__ float As[16][33];
    __shared__ float Ws[16 * 128];
    int tid = threadIdx.x;
    int row0 = blockIdx.x * 32;
    const float* hp = h + (size_t)row0 * 64;
    float acc[2][8] = {};
    int tx = tid & 15, ty = tid >> 4;
    int lr = tid >> 3;
    int lk = (tid & 7) * 2;
    int wk = tid >> 4;
    int wc = (tid & 15) * 8;
    for (int kt = 0; kt < 4; kt++) {
        int c0 = kt * 16;
        float2 a2 = *(const float2*)&hp[lr * 64 + c0 + lk];
        const float4* wsrc = (const float4*)&W1cat[(size_t)(kt * 16 + wk) * 128 + wc];
        float4 w0 = wsrc[0], w1 = wsrc[1];
        As[lk][lr] = a2.x;
        As[lk + 1][lr] = a2.y;
        *(float4*)&Ws[wk * 128 + wc] = w0;
        *(float4*)&Ws[wk * 128 + wc + 4] = w1;
        __syncthreads();
#pragma unroll
        for (int kk = 0; kk < 16; kk++) {
            float a0 = As[kk][ty * 2 + 0];
            float a1 = As[kk][ty * 2 + 1];
            float4 p0 = *(const float4*)&Ws[kk * 128 + tx * 8];
            float4 p1 = *(const float4*)&Ws[kk * 128 + tx * 8 + 4];
            float w[8] = { p0.x, p0.y, p0.z, p0.w, p1.x, p1.y, p1.z, p1.w };
#pragma unroll
            for (int cc = 0; cc < 8; cc++) {
                acc[0][cc] += a0 * w[cc];
                acc[1][cc] += a1 * w[cc];
            }
        }
        __syncthreads();
    }
#pragma unroll
    for (int rr = 0; rr < 2; rr++) {
        int row = row0 + ty * 2 + rr;
#pragma unroll
        for (int cc = 0; cc < 8; cc++) {
            int col = tx * 8 + cc;
            float v = acc[rr][cc];
            if (col < 64) sproj[(size_t)row * 64 + col] = v + b1[col];
            else tproj[(size_t)row * 64 + (col - 64)] = v;
        }
    }
}

// ---------------- logits ----------------
__global__ __launch_bounds__(256) void k_logits(
        const float* __restrict__ sproj, const float* __restrict__ tproj,
        const float* __restrict__ W2, const float* __restrict__ b2,
        float* __restrict__ out) {
    __shared__ float sp[32 * 64];
    __shared__ float tp[64 * 65];
    __shared__ float w2s[64];
    int tid = threadIdx.x;
    int bb = blockIdx.x >> 7;
    int st = (blockIdx.x >> 3) & 15;
    int tt = blockIdx.x & 7;
    const float* spg = sproj + ((size_t)bb * Nn + st * 32) * 64;
    const float* tpg = tproj + ((size_t)bb * Nn + tt * 64) * 64;
    for (int i = tid; i < 2048; i += 256) sp[i] = spg[i];
    for (int i = tid; i < 4096; i += 256) {
        int tl = i >> 6, hh = i & 63;
        tp[tl * 65 + hh] = tpg[i];
    }
    if (tid < 64) w2s[tid] = W2[tid];
    __syncthreads();
    float bias = *b2;
    int tl = tid & 63, sg = tid >> 6;
    for (int si = 0; si < 8; si++) {
        int s = sg * 8 + si;
        float acc = bias;
#pragma unroll 8
        for (int hh = 0; hh < 64; hh++) {
            float v = sp[s * 64 + hh] + tp[tl * 65 + hh];
            acc += fmaxf(v, 0.f) * w2s[hh];
        }
        out[(size_t)bb * Nn * Nn + (size_t)(st * 32 + s) * Nn + tt * 64 + tl] = acc;
    }
}

// ---------------- host ----------------
extern "C" void kernel_launch(void* const* d_in, const int* in_sizes, int n_in,
                              void* d_out, int out_size, void* d_ws, size_t ws_size,
                              hipStream_t stream) {
    const float* x  = (const float*)d_in[0];
    const float* ew = (const float*)d_in[1];
    const float* Wx = (const float*)d_in[2];
    const float* bx = (const float*)d_in[3];
    const float* Wh = (const float*)d_in[4];
    const float* bh = (const float*)d_in[5];
    const float* W1 = (const float*)d_in[6];
    const float* b1 = (const float*)d_in[7];
    const float* W2 = (const float*)d_in[8];
    const float* b2 = (const float*)d_in[9];
    const int* ei   = (const int*)d_in[10];
    const int* esrc = ei;
    const int* edst = ei + En;

    float* ws = (float*)d_ws;
    float* deg   = ws + OFF_DEG;
    float* dinv  = ws + OFF_DINV;
    float* L1d   = ws + OFF_L1D;
    float* L2d   = ws + OFF_L2D;
    float* WzrC  = ws + OFF_WZR;
    float* WhC   = ws + OFF_WHT;
    float* bzr   = ws + OFF_BZR;
    float* bht   = ws + OFF_BHT;
    float* W1cat = ws + OFF_W1C;
    float* T1x   = ws + OFF_T1X;
    float* T2x   = ws + OFF_T2X;
    float* h     = ws + OFF_H;
    float* z     = ws + OFF_Z;
    float* hr    = ws + OFF_HR;
    float* sproj = ws + OFF_SP;
    float* tproj = ws + OFF_TP;
    ushort* AfH  = (ushort*)(ws + OFF_LFH);
    ushort* AfL  = (ushort*)(ws + OFF_LFL);
    ushort* hTh  = (ushort*)(ws + OFF_HTH);
    ushort* hTl  = (ushort*)(ws + OFF_HTL);
    ushort* hrTh = (ushort*)(ws + OFF_HRTH);
    ushort* hrTl = (ushort*)(ws + OFF_HRTL);
    // W-fragments alias the sproj region (dead until k_proj, which runs after recurrence)
    ushort* WzFH = (ushort*)(ws + OFF_SP);
    ushort* WzFL = WzFH + 98304;
    ushort* WhFH = WzFL + 98304;
    ushort* WhFL = WhFH + 49152;
    float* out   = (float*)d_out;

    hipMemsetAsync(deg, 0, 512 * sizeof(float), stream);
    hipMemsetAsync(L1d, 0, (size_t)Nn * Nn * sizeof(float), stream);
    hipMemsetAsync(h, 0, (size_t)Bn * NC * sizeof(float), stream);
    hipMemsetAsync(hTh, 0, 262144 * sizeof(ushort), stream);
    hipMemsetAsync(hTl, 0, 262144 * sizeof(ushort), stream);

    k_deg<<<64, 256, 0, stream>>>(ew, esrc, deg);
    k_dinv<<<2, 256, 0, stream>>>(deg, dinv);
    k_nwdense<<<64, 256, 0, stream>>>(ew, esrc, edst, dinv, L1d);
    k_l2<<<64, 256, 0, stream>>>(L1d, L2d);
    k_lfrag<<<2048, 256, 0, stream>>>(L1d, L2d, AfH, AfL);
    k_repack<<<(156032 + 255) / 256, 256, 0, stream>>>(Wx, bx, Wh, bh, W1,
                                                       WzrC, WhC, bzr, bht, W1cat);
    k_wfrag<<<(147456 + 255) / 256, 256, 0, stream>>>(WzrC, WhC, WzFH, WzFL, WhFH, WhFL);

    // T1x/T2x via MFMA (replaces fp32 k_lmm2)
    k_lxm<<<512, 256, 0, stream>>>(AfH, AfL, x, T1x, T2x);

    for (int t = 0; t < Tn; t++) {
        for (int l = 0; l < Ln; l++) {
            k_cell1<<<256, 256, 0, stream>>>(h, x, T1x, T2x, AfH, AfL, hTh, hTl,
                                             WzFH + (size_t)l * 49152,
                                             WzFL + (size_t)l * 49152,
                                             bzr + l * 128, z, hr, hrTh, hrTl, t);
            k_cell2<<<256, 256, 0, stream>>>(hr, x, T1x, T2x, AfH, AfL, hrTh, hrTl,
                                             WhFH + (size_t)l * 24576,
                                             WhFL + (size_t)l * 24576,
                                             bht + l * 64, z, h, hTh, hTl, t);
        }
    }

    k_proj<<<128, 256, 0, stream>>>(h, W1cat, b1, sproj, tproj);
    k_logits<<<Bn * 16 * 8, 256, 0, stream>>>(sproj, tproj, W2, b2, out);
}

// Round 10
// 1067.555 us; speedup vs baseline: 3.0341x; 3.0341x over previous
//
#include <hip/hip_runtime.h>

typedef unsigned short ushort;
typedef __attribute__((ext_vector_type(8))) short short8;
typedef __attribute__((ext_vector_type(4))) float f32x4;

// Problem constants
constexpr int Bn = 8, Tn = 16, Nn = 512, Cn = 64, Hn = 64, En = 16384, Ln = 2;
constexpr int NC = Nn * Cn;           // 32768
constexpr int MROWS = Bn * Nn;        // 4096

// ---------------- workspace layout (in floats) ----------------
constexpr size_t OFF_DEG  = 0;
constexpr size_t OFF_DINV = 512;
constexpr size_t OFF_L1D  = 1024;                         // 512*512
constexpr size_t OFF_L2D  = OFF_L1D + 262144;
constexpr size_t OFF_WZR  = OFF_L2D + 262144;             // 2*384*128
constexpr size_t OFF_WHT  = OFF_WZR + 2*384*128;          // 2*384*64
constexpr size_t OFF_BZR  = OFF_WHT + 2*384*64;
constexpr size_t OFF_BHT  = OFF_BZR + 256;
constexpr size_t OFF_W1C  = OFF_BHT + 128;                // 8192
constexpr size_t OFF_T1X  = OFF_W1C + 8192;               // B*T*N*C
constexpr size_t OFF_T2X  = OFF_T1X + (size_t)Bn*Tn*NC;
constexpr size_t OFF_H    = OFF_T2X + (size_t)Bn*Tn*NC;   // B*N*H
constexpr size_t OFF_Z    = OFF_H   + (size_t)Bn*NC;
constexpr size_t OFF_HR   = OFF_Z   + (size_t)Bn*NC;
constexpr size_t OFF_SP   = OFF_HR  + (size_t)Bn*NC;      // sproj; W-frags alias this
constexpr size_t OFF_TP   = OFF_SP  + (size_t)MROWS*Hn;   //   (recurrence-only lifetime)
constexpr size_t OFF_LFH  = OFF_TP  + (size_t)MROWS*Hn;   // L-frags bf16 hi/lo
constexpr size_t OFF_LFL  = OFF_LFH + 262144;
constexpr size_t OFF_HTH  = OFF_LFL + 262144;             // transposed bf16 h/hr hi/lo
constexpr size_t OFF_HTL  = OFF_HTH + 131072;
constexpr size_t OFF_HRTH = OFF_HTL + 131072;
constexpr size_t OFF_HRTL = OFF_HRTH + 131072;
constexpr size_t OFF_END  = OFF_HRTL + 131072;

__device__ __forceinline__ ushort f2bf(float f) {
    unsigned u = __float_as_uint(f);
    u = u + 0x7FFF + ((u >> 16) & 1);
    return (ushort)(u >> 16);
}
__device__ __forceinline__ float bf2f(ushort h) {
    return __uint_as_float(((unsigned)h) << 16);
}
// fragment-linear LDS layout for a 16x64 bf16 A-operand panel:
// value (m,k) lives at (k>>5)*512 + ((k>>3)&3)*128 + m*8 + (k&7)
__device__ __forceinline__ int fragaddr(int m, int k) {
    return ((k >> 5) << 9) + (((k >> 3) & 3) << 7) + (m << 3) + (k & 7);
}

#define MFMA16(a, b, c) __builtin_amdgcn_mfma_f32_16x16x32_bf16((a), (b), (c), 0, 0, 0)

// ---------------- setup kernels ----------------
__global__ void k_deg(const float* __restrict__ w, const int* __restrict__ src,
                      float* __restrict__ deg) {
    int e = blockIdx.x * 256 + threadIdx.x;
    if (e < En) atomicAdd(&deg[src[e]], w[e]);
}

__global__ void k_dinv(const float* __restrict__ deg, float* __restrict__ dinv) {
    int n = blockIdx.x * 256 + threadIdx.x;
    if (n < Nn) {
        float d = deg[n];
        dinv[n] = d > 0.f ? rsqrtf(fmaxf(d, 1e-12f)) : 0.f;
    }
}

__global__ void k_nwdense(const float* __restrict__ w, const int* __restrict__ src,
                          const int* __restrict__ dst, const float* __restrict__ dinv,
                          float* __restrict__ L1d) {
    int e = blockIdx.x * 256 + threadIdx.x;
    if (e < En) {
        int s = src[e], d = dst[e];
        float nw = -w[e] * dinv[s] * dinv[d];
        atomicAdd(&L1d[d * Nn + s], nw);
    }
}

// L2 = 2*(L1@L1) - I
__global__ __launch_bounds__(256) void k_l2(const float* __restrict__ A,
                                            float* __restrict__ C) {
    __shared__ float As[64][33];
    __shared__ float Bs[32][65];
    int t = threadIdx.x;
    int i0 = (blockIdx.x >> 3) * 64;
    int j0 = (blockIdx.x & 7) * 64;
    int tx = t & 15, ty = t >> 4;
    float acc[4][4] = {};
    int ar = t >> 2, ac = (t & 3) * 8;
    int br = t >> 3, bc = (t & 7) * 8;
    for (int kc = 0; kc < 512; kc += 32) {
        float4 a0 = *(const float4*)&A[(size_t)(i0 + ar) * 512 + kc + ac];
        float4 a1 = *(const float4*)&A[(size_t)(i0 + ar) * 512 + kc + ac + 4];
        float4 b0 = *(const float4*)&A[(size_t)(kc + br) * 512 + j0 + bc];
        float4 b1 = *(const float4*)&A[(size_t)(kc + br) * 512 + j0 + bc + 4];
        As[ar][ac+0]=a0.x; As[ar][ac+1]=a0.y; As[ar][ac+2]=a0.z; As[ar][ac+3]=a0.w;
        As[ar][ac+4]=a1.x; As[ar][ac+5]=a1.y; As[ar][ac+6]=a1.z; As[ar][ac+7]=a1.w;
        Bs[br][bc+0]=b0.x; Bs[br][bc+1]=b0.y; Bs[br][bc+2]=b0.z; Bs[br][bc+3]=b0.w;
        Bs[br][bc+4]=b1.x; Bs[br][bc+5]=b1.y; Bs[br][bc+6]=b1.z; Bs[br][bc+7]=b1.w;
        __syncthreads();
#pragma unroll 8
        for (int kk = 0; kk < 32; kk++) {
            float av[4], bv[4];
#pragma unroll
            for (int r = 0; r < 4; r++) av[r] = As[ty * 4 + r][kk];
#pragma unroll
            for (int c = 0; c < 4; c++) bv[c] = Bs[kk][tx * 4 + c];
#pragma unroll
            for (int r = 0; r < 4; r++)
#pragma unroll
                for (int c = 0; c < 4; c++) acc[r][c] += av[r] * bv[c];
        }
        __syncthreads();
    }
#pragma unroll
    for (int r = 0; r < 4; r++)
#pragma unroll
        for (int c = 0; c < 4; c++) {
            int i = i0 + ty * 4 + r, j = j0 + tx * 4 + c;
            C[(size_t)i * 512 + j] = 2.f * acc[r][c] - (i == j ? 1.f : 0.f);
        }
}

// L1/L2 -> bf16 split A-fragments; idx = ((mat*32+rb)*16 + kc)*512 + lane*8 + j
__global__ void k_lfrag(const float* __restrict__ L1, const float* __restrict__ L2,
                        ushort* __restrict__ AfH, ushort* __restrict__ AfL) {
    int idx = blockIdx.x * 256 + threadIdx.x;   // 0..524287
    int j = idx & 7;
    int lane = (idx >> 3) & 63;
    int kc = (idx >> 9) & 15;
    int rb = (idx >> 13) & 31;
    int mat = idx >> 18;
    int row = rb * 16 + (lane & 15);
    int k = kc * 32 + (lane >> 4) * 8 + j;
    float v = (mat ? L2 : L1)[(size_t)row * 512 + k];
    ushort hi = f2bf(v);
    AfH[idx] = hi;
    AfL[idx] = f2bf(v - bf2f(hi));
}

// Wzr/Wht -> bf16 split B-fragments: idx = ((l*CT + ct)*12 + kc)*512 + lane*8 + j
__global__ void k_wfrag(const float* __restrict__ WzrC, const float* __restrict__ WhC,
                        ushort* __restrict__ WzFH, ushort* __restrict__ WzFL,
                        ushort* __restrict__ WhFH, ushort* __restrict__ WhFL) {
    int idx = blockIdx.x * 256 + threadIdx.x;
    if (idx < 98304) {
        int l = idx / 49152, off = idx % 49152;
        int tile = off >> 9, r = off & 511;
        int lane = r >> 3, j = r & 7;
        int ct = tile / 12, kc = tile % 12;
        int k = kc * 32 + (lane >> 4) * 8 + j;
        int n = ct * 16 + (lane & 15);
        float v = WzrC[(size_t)l * 49152 + k * 128 + n];
        ushort hi = f2bf(v);
        WzFH[idx] = hi;
        WzFL[idx] = f2bf(v - bf2f(hi));
    } else if (idx < 147456) {
        int t2 = idx - 98304;
        int l = t2 / 24576, off = t2 % 24576;
        int tile = off >> 9, r = off & 511;
        int lane = r >> 3, j = r & 7;
        int ct = tile / 12, kc = tile % 12;
        int k = kc * 32 + (lane >> 4) * 8 + j;
        int n = ct * 16 + (lane & 15);
        float v = WhC[(size_t)l * 24576 + k * 64 + n];
        ushort hi = f2bf(v);
        WhFH[t2] = hi;
        WhFL[t2] = f2bf(v - bf2f(hi));
    }
}

// ---------------- MFMA T1x/T2x: o1 = L1@x, o2 = L2@x per slice ----------------
// 512 blocks = 128 slices x 4 rowgroups(128 rows). FIXED vs round 9: kc loop is
// fully unrolled (all buffer indices static) and A-frags are explicit scalar
// short8 vars — no dynamically-indexed register arrays (those demoted to
// scratch: 39 GB FETCH, 2.2 ms).
__global__ __launch_bounds__(256) void k_lxm(
        const ushort* __restrict__ AfH, const ushort* __restrict__ AfL,
        const float* __restrict__ in, float* __restrict__ o1, float* __restrict__ o2) {
    __shared__ ushort Bh[2][2176];   // [buf][n*34 + k] (pad 34 halves)
    __shared__ ushort Bl[2][2176];
    int slice = blockIdx.x >> 2;
    int rg = blockIdx.x & 3;
    const float* xs = in + (size_t)slice * NC;
    int tid = threadIdx.x;
    int lane = tid & 63, wav = tid >> 6;
    int quad = lane >> 4, l15 = lane & 15;
    int sn = tid & 63, skq = tid >> 6;
    int rt0 = rg * 8 + wav * 2;
    size_t ab00 = ((size_t)(rt0 + 0) * 16) * 512 + lane * 8;       // rt 0, L1
    size_t ab10 = ((size_t)(rt0 + 1) * 16) * 512 + lane * 8;       // rt 1, L1
    size_t ab01 = ((size_t)(32 + rt0 + 0) * 16) * 512 + lane * 8;  // rt 0, L2
    size_t ab11 = ((size_t)(32 + rt0 + 1) * 16) * 512 + lane * 8;  // rt 1, L2
    f32x4 acc[2][2][4];
#pragma unroll
    for (int r = 0; r < 2; r++)
#pragma unroll
        for (int m = 0; m < 2; m++)
#pragma unroll
            for (int n = 0; n < 4; n++) acc[r][m][n] = (f32x4){0.f, 0.f, 0.f, 0.f};

    // stage chunk 0 into buf 0
    {
        short8 hi8, lo8;
#pragma unroll
        for (int i = 0; i < 8; i++) {
            float v = xs[(size_t)(skq * 8 + i) * 64 + sn];
            ushort hv = f2bf(v);
            hi8[i] = (short)hv;
            lo8[i] = (short)f2bf(v - bf2f(hv));
        }
        *(short8*)&Bh[0][sn * 34 + skq * 8] = hi8;
        *(short8*)&Bl[0][sn * 34 + skq * 8] = lo8;
    }
    __syncthreads();
#pragma unroll
    for (int kc = 0; kc < 16; kc++) {
        const int cur = kc & 1;            // static after full unroll
        float sv[8];
        if (kc < 15) {
#pragma unroll
            for (int i = 0; i < 8; i++)
                sv[i] = xs[(size_t)((kc + 1) * 32 + skq * 8 + i) * 64 + sn];
        }
        size_t o = (size_t)kc * 512;
        short8 h00 = *(const short8*)&AfH[ab00 + o];
        short8 g00 = *(const short8*)&AfL[ab00 + o];
        short8 h10 = *(const short8*)&AfH[ab10 + o];
        short8 g10 = *(const short8*)&AfL[ab10 + o];
        short8 h01 = *(const short8*)&AfH[ab01 + o];
        short8 g01 = *(const short8*)&AfL[ab01 + o];
        short8 h11 = *(const short8*)&AfH[ab11 + o];
        short8 g11 = *(const short8*)&AfL[ab11 + o];
#pragma unroll
        for (int nt = 0; nt < 4; nt++) {
            short8 bh8 = *(const short8*)&Bh[cur][(nt * 16 + l15) * 34 + quad * 8];
            short8 bl8 = *(const short8*)&Bl[cur][(nt * 16 + l15) * 34 + quad * 8];
            acc[0][0][nt] = MFMA16(h00, bh8, acc[0][0][nt]);
            acc[0][0][nt] = MFMA16(h00, bl8, acc[0][0][nt]);
            acc[0][0][nt] = MFMA16(g00, bh8, acc[0][0][nt]);
            acc[1][0][nt] = MFMA16(h10, bh8, acc[1][0][nt]);
            acc[1][0][nt] = MFMA16(h10, bl8, acc[1][0][nt]);
            acc[1][0][nt] = MFMA16(g10, bh8, acc[1][0][nt]);
            acc[0][1][nt] = MFMA16(h01, bh8, acc[0][1][nt]);
            acc[0][1][nt] = MFMA16(h01, bl8, acc[0][1][nt]);
            acc[0][1][nt] = MFMA16(g01, bh8, acc[0][1][nt]);
            acc[1][1][nt] = MFMA16(h11, bh8, acc[1][1][nt]);
            acc[1][1][nt] = MFMA16(h11, bl8, acc[1][1][nt]);
            acc[1][1][nt] = MFMA16(g11, bh8, acc[1][1][nt]);
        }
        if (kc < 15) {
            short8 hi8, lo8;
#pragma unroll
            for (int i = 0; i < 8; i++) {
                ushort hv = f2bf(sv[i]);
                hi8[i] = (short)hv;
                lo8[i] = (short)f2bf(sv[i] - bf2f(hv));
            }
            *(short8*)&Bh[cur ^ 1][sn * 34 + skq * 8] = hi8;
            *(short8*)&Bl[cur ^ 1][sn * 34 + skq * 8] = lo8;
        }
        __syncthreads();
    }
    float* os1 = o1 + (size_t)slice * NC;
    float* os2 = o2 + (size_t)slice * NC;
#pragma unroll
    for (int r = 0; r < 2; r++)
#pragma unroll
        for (int nt = 0; nt < 4; nt++)
#pragma unroll
            for (int reg = 0; reg < 4; reg++) {
                size_t row = (size_t)((rt0 + r) * 16 + quad * 4 + reg);
                os1[row * 64 + nt * 16 + l15] = acc[r][0][nt][reg];
                os2[row * 64 + nt * 16 + l15] = acc[r][1][nt][reg];
            }
}

// repack weights
__global__ void k_repack(const float* __restrict__ Wx, const float* __restrict__ bx,
                         const float* __restrict__ Wh, const float* __restrict__ bh,
                         const float* __restrict__ W1,
                         float* __restrict__ WzrC, float* __restrict__ WhC,
                         float* __restrict__ bzr, float* __restrict__ bht,
                         float* __restrict__ W1cat) {
    int idx = blockIdx.x * 256 + threadIdx.x;
    if (idx < 98304) {
        int l = idx / 49152, r = idx % 49152;
        int k = r / 128, j = r % 128;
        int g = j >> 6, hh = j & 63;
        int kc, c; const float* s;
        if (k < 192) { kc = k / 64; c = k % 64; s = Wh; }
        else { kc = (k - 192) / 64; c = (k - 192) % 64; s = Wx; }
        WzrC[idx] = s[((((size_t)(l*3 + g))*3 + kc)*64 + c)*64 + hh];
    } else if (idx < 147456) {
        int tI = idx - 98304;
        int l = tI / 24576, r = tI % 24576;
        int k = r / 64, hh = r % 64;
        int kc, c; const float* s;
        if (k < 192) { kc = k / 64; c = k % 64; s = Wh; }
        else { kc = (k - 192) / 64; c = (k - 192) % 64; s = Wx; }
        WhC[tI] = s[((((size_t)(l*3 + 2))*3 + kc)*64 + c)*64 + hh];
    } else if (idx < 147712) {
        int tI = idx - 147456;
        int l = tI >> 7, j = tI & 127;
        int g = j >> 6, hh = j & 63;
        bzr[tI] = bh[(l*3 + g)*64 + hh] + bx[(l*3 + g)*64 + hh];
    } else if (idx < 147840) {
        int tI = idx - 147712;
        int l = tI >> 6, hh = tI & 63;
        bht[tI] = bh[(l*3 + 2)*64 + hh] + bx[(l*3 + 2)*64 + hh];
    } else if (idx < 156032) {
        int tI = idx - 147840;
        int c = tI >> 7, j = tI & 127;
        W1cat[tI] = (j < 64) ? W1[c*64 + j] : W1[(64 + c)*64 + (j - 64)];
    }
}

// ================= full-MFMA cell kernels: 256 blocks x 16 rows =================
// LDS (floats): AH@0 (6x1024 halves = 3072 fl) | AL@3072 | PRED@6144 (2048) | HRS@8192 (1024)

// common: stage segs 0,3,4,5 (fp32 global -> bf16 hi/lo frags)
__device__ __forceinline__ void stage_segs(
        ushort* AH, ushort* AL, const float* s0, const float* x,
        const float* t1x, const float* t2x, size_t xoff, int tid) {
    int p = tid * 4;
    int m = p >> 6, kb = p & 63;
    int fa = fragaddr(m, kb);
    const float* srcs[4] = { s0, x + xoff, t1x + xoff, t2x + xoff };
    const int sidx[4] = { 0, 3, 4, 5 };
#pragma unroll
    for (int q = 0; q < 4; q++) {
        float4 v = *(const float4*)&srcs[q][(size_t)m * 64 + kb];
        float vv[4] = { v.x, v.y, v.z, v.w };
        int base = sidx[q] * 1024 + fa;
#pragma unroll
        for (int j = 0; j < 4; j++) {
            ushort hi = f2bf(vv[j]);
            AH[base + j] = hi;
            AL[base + j] = f2bf(vv[j] - bf2f(hi));
        }
    }
}

// phase A: U1 = L1[rows,:]@src, U2 = L2[rows,:]@src via split-bf16 MFMA.
// Depth-4 prefetch; 6 independent accumulators (no dependent MFMA chains).
__device__ __forceinline__ void phase_A16(
        ushort* AH, ushort* AL,
        const ushort* __restrict__ sTh, const ushort* __restrict__ sTl,
        const ushort* __restrict__ AfH, const ushort* __restrict__ AfL,
        int rowblk, int tid) {
    int lane = tid & 63, wav = tid >> 6;
    int quad = lane >> 4, l15 = lane & 15;
    size_t ab1 = ((size_t)rowblk * 16) * 512 + lane * 8;
    size_t ab2 = ((size_t)(32 + rowblk) * 16) * 512 + lane * 8;
    size_t bb = (size_t)(wav * 16 + l15) * 512 + quad * 8;
    f32x4 p1a = {0.f,0.f,0.f,0.f}, p1b = p1a, p1c = p1a;
    f32x4 p2a = p1a, p2b = p1a, p2c = p1a;
    short8 a1h[4], a1l[4], a2h[4], a2l[4], bh[4], bl[4];
#pragma unroll
    for (int s = 0; s < 4; s++) {
        size_t o = (size_t)s * 512;
        a1h[s] = *(const short8*)&AfH[ab1 + o];
        a1l[s] = *(const short8*)&AfL[ab1 + o];
        a2h[s] = *(const short8*)&AfH[ab2 + o];
        a2l[s] = *(const short8*)&AfL[ab2 + o];
        bh[s]  = *(const short8*)&sTh[bb + s * 32];
        bl[s]  = *(const short8*)&sTl[bb + s * 32];
    }
#pragma unroll
    for (int kc = 0; kc < 16; kc++) {
        int s = kc & 3;
        p1a = MFMA16(a1h[s], bh[s], p1a);
        p1b = MFMA16(a1h[s], bl[s], p1b);
        p1c = MFMA16(a1l[s], bh[s], p1c);
        p2a = MFMA16(a2h[s], bh[s], p2a);
        p2b = MFMA16(a2h[s], bl[s], p2b);
        p2c = MFMA16(a2l[s], bh[s], p2c);
        if (kc + 4 < 16) {
            size_t o = (size_t)(kc + 4) * 512;
            a1h[s] = *(const short8*)&AfH[ab1 + o];
            a1l[s] = *(const short8*)&AfL[ab1 + o];
            a2h[s] = *(const short8*)&AfH[ab2 + o];
            a2l[s] = *(const short8*)&AfL[ab2 + o];
            bh[s]  = *(const short8*)&sTh[bb + (kc + 4) * 32];
            bl[s]  = *(const short8*)&sTl[bb + (kc + 4) * 32];
        }
    }
    int colA = wav * 16 + l15;
#pragma unroll
    for (int reg = 0; reg < 4; reg++) {
        int row = quad * 4 + reg;
        float u1 = p1a[reg] + p1b[reg] + p1c[reg];
        float u2 = p2a[reg] + p2b[reg] + p2c[reg];
        ushort h1 = f2bf(u1), h2 = f2bf(u2);
        int fa1 = 1024 + fragaddr(row, colA);
        int fa2 = 2048 + fragaddr(row, colA);
        AH[fa1] = h1; AL[fa1] = f2bf(u1 - bf2f(h1));
        AH[fa2] = h2; AL[fa2] = f2bf(u2 - bf2f(h2));
    }
}

// stage1: z,r = sigmoid(A@Wzr + b); z->global; hr = h*r -> global fp32 + bf16 transposed
__global__ __launch_bounds__(256) void k_cell1(
        const float* __restrict__ h, const float* __restrict__ x,
        const float* __restrict__ t1x, const float* __restrict__ t2x,
        const ushort* __restrict__ AfH, const ushort* __restrict__ AfL,
        const ushort* __restrict__ hTh, const ushort* __restrict__ hTl,
        const ushort* __restrict__ WFH, const ushort* __restrict__ WFL,
        const float* __restrict__ bias,
        float* __restrict__ z, float* __restrict__ hr,
        ushort* __restrict__ hrTh, ushort* __restrict__ hrTl, int t) {
    __shared__ float lds[9216];
    ushort* AH = (ushort*)lds;
    ushort* AL = (ushort*)(lds + 3072);
    float* PRED = lds + 6144;
    float* HRS  = lds + 8192;
    int tid = threadIdx.x;
    int b = blockIdx.x >> 5;
    int rowblk = blockIdx.x & 31;
    int n0 = rowblk * 16;
    size_t hoff = ((size_t)b * Nn + n0) * 64;
    size_t xoff = ((size_t)(b * Tn + t) * Nn + n0) * 64;

    stage_segs(AH, AL, h + hoff, x, t1x, t2x, xoff, tid);
    phase_A16(AH, AL, hTh + (size_t)b * 32768, hTl + (size_t)b * 32768,
              AfH, AfL, rowblk, tid);
    __syncthreads();

    // phase B1: zr[16][128] = A[16][384] @ Wzr — depth-4 W / depth-2 A, split accs
    int lane = tid & 63, wav = tid >> 6;
    int quad = lane >> 4, l15 = lane & 15;
    {
        int abase = quad * 128 + l15 * 8;
        size_t w0 = ((size_t)wav * 12) * 512 + lane * 8;
        size_t w1 = ((size_t)(4 + wav) * 12) * 512 + lane * 8;
        f32x4 q0a = {0.f,0.f,0.f,0.f}, q0b = q0a, q0c = q0a;
        f32x4 q1a = q0a, q1b = q0a, q1c = q0a;
        short8 ah[2], al[2], w0h[4], w0l[4], w1h[4], w1l[4];
#pragma unroll
        for (int s = 0; s < 2; s++) {
            ah[s] = *(const short8*)&AH[abase + s * 512];
            al[s] = *(const short8*)&AL[abase + s * 512];
        }
#pragma unroll
        for (int s = 0; s < 4; s++) {
            size_t o = (size_t)s * 512;
            w0h[s] = *(const short8*)&WFH[w0 + o];
            w0l[s] = *(const short8*)&WFL[w0 + o];
            w1h[s] = *(const short8*)&WFH[w1 + o];
            w1l[s] = *(const short8*)&WFL[w1 + o];
        }
#pragma unroll
        for (int kt = 0; kt < 12; kt++) {
            int sa = kt & 1, sw = kt & 3;
            q0a = MFMA16(ah[sa], w0h[sw], q0a);
            q0b = MFMA16(ah[sa], w0l[sw], q0b);
            q0c = MFMA16(al[sa], w0h[sw], q0c);
            q1a = MFMA16(ah[sa], w1h[sw], q1a);
            q1b = MFMA16(ah[sa], w1l[sw], q1b);
            q1c = MFMA16(al[sa], w1h[sw], q1c);
            if (kt + 2 < 12) {
                ah[sa] = *(const short8*)&AH[abase + (kt + 2) * 512];
                al[sa] = *(const short8*)&AL[abase + (kt + 2) * 512];
            }
            if (kt + 4 < 12) {
                size_t o = (size_t)(kt + 4) * 512;
                w0h[sw] = *(const short8*)&WFH[w0 + o];
                w0l[sw] = *(const short8*)&WFL[w0 + o];
                w1h[sw] = *(const short8*)&WFH[w1 + o];
                w1l[sw] = *(const short8*)&WFL[w1 + o];
            }
        }
#pragma unroll
        for (int reg = 0; reg < 4; reg++) {
            int row = quad * 4 + reg;
            PRED[row * 128 + wav * 16 + l15] = q0a[reg] + q0b[reg] + q0c[reg];
            PRED[row * 128 + 64 + wav * 16 + l15] = q1a[reg] + q1b[reg] + q1c[reg];
        }
    }
    __syncthreads();
    for (int i = tid; i < 2048; i += 256) {
        int r = i >> 7, c = i & 127;
        float v = PRED[i] + bias[c];
        float s = 1.f / (1.f + __expf(-v));
        size_t grow = ((size_t)(b * Nn + n0 + r)) * 64;
        if (c < 64) {
            z[grow + c] = s;
        } else {
            int c2 = c - 64;
            int fa = fragaddr(r, c2);
            float hv = bf2f(AH[fa]) + bf2f(AL[fa]);
            float hrv = hv * s;
            hr[grow + c2] = hrv;
            HRS[r * 64 + c2] = hrv;
        }
    }
    __syncthreads();
    for (int i = tid; i < 1024; i += 256) {
        int c = i >> 4, r = i & 15;
        float hrv = HRS[r * 64 + c];
        size_t gi = (size_t)b * 32768 + (size_t)c * 512 + n0 + r;
        ushort hi = f2bf(hrv);
        hrTh[gi] = hi;
        hrTl[gi] = f2bf(hrv - bf2f(hi));
    }
}

// stage2: ht = tanh(A@Wht + b); h = z*h + (1-z)*ht -> global fp32 + bf16 transposed
__global__ __launch_bounds__(256) void k_cell2(
        const float* __restrict__ hrp, const float* __restrict__ x,
        const float* __restrict__ t1x, const float* __restrict__ t2x,
        const ushort* __restrict__ AfH, const ushort* __restrict__ AfL,
        const ushort* __restrict__ hrTh, const ushort* __restrict__ hrTl,
        const ushort* __restrict__ WFH, const ushort* __restrict__ WFL,
        const float* __restrict__ bias,
        const float* __restrict__ z, float* __restrict__ h,
        ushort* __restrict__ hTh, ushort* __restrict__ hTl, int t) {
    __shared__ float lds[9216];
    ushort* AH = (ushort*)lds;
    ushort* AL = (ushort*)(lds + 3072);
    float* PRED = lds + 6144;
    float* HRS  = lds + 8192;
    int tid = threadIdx.x;
    int b = blockIdx.x >> 5;
    int rowblk = blockIdx.x & 31;
    int n0 = rowblk * 16;
    size_t hoff = ((size_t)b * Nn + n0) * 64;
    size_t xoff = ((size_t)(b * Tn + t) * Nn + n0) * 64;

    stage_segs(AH, AL, hrp + hoff, x, t1x, t2x, xoff, tid);
    phase_A16(AH, AL, hrTh + (size_t)b * 32768, hrTl + (size_t)b * 32768,
              AfH, AfL, rowblk, tid);
    __syncthreads();

    // phase B2: ht[16][64] = A[16][384] @ Wht — depth-4 W / depth-2 A, split accs
    int lane = tid & 63, wav = tid >> 6;
    int quad = lane >> 4, l15 = lane & 15;
    {
        int abase = quad * 128 + l15 * 8;
        size_t w0 = ((size_t)wav * 12) * 512 + lane * 8;
        f32x4 qa = {0.f,0.f,0.f,0.f}, qb = qa, qc = qa;
        short8 ah[2], al[2], wh[4], wl[4];
#pragma unroll
        for (int s = 0; s < 2; s++) {
            ah[s] = *(const short8*)&AH[abase + s * 512];
            al[s] = *(const short8*)&AL[abase + s * 512];
        }
#pragma unroll
        for (int s = 0; s < 4; s++) {
            wh[s] = *(const short8*)&WFH[w0 + (size_t)s * 512];
            wl[s] = *(const short8*)&WFL[w0 + (size_t)s * 512];
        }
#pragma unroll
        for (int kt = 0; kt < 12; kt++) {
            int sa = kt & 1, sw = kt & 3;
            qa = MFMA16(ah[sa], wh[sw], qa);
            qb = MFMA16(ah[sa], wl[sw], qb);
            qc = MFMA16(al[sa], wh[sw], qc);
            if (kt + 2 < 12) {
                ah[sa] = *(const short8*)&AH[abase + (kt + 2) * 512];
                al[sa] = *(const short8*)&AL[abase + (kt + 2) * 512];
            }
            if (kt + 4 < 12) {
                size_t o = (size_t)(kt + 4) * 512;
                wh[sw] = *(const short8*)&WFH[w0 + o];
                wl[sw] = *(const short8*)&WFL[w0 + o];
            }
        }
#pragma unroll
        for (int reg = 0; reg < 4; reg++)
            PRED[(quad * 4 + reg) * 64 + wav * 16 + l15] = qa[reg] + qb[reg] + qc[reg];
    }
    __syncthreads();
    for (int i = tid; i < 1024; i += 256) {
        int c = i & 63;
        float ht = tanhf(PRED[i] + bias[c]);
        size_t p = ((size_t)(b * Nn + n0 + (i >> 6))) * 64 + c;
        float zz = z[p], hold = h[p];
        float hn = zz * hold + (1.f - zz) * ht;
        h[p] = hn;
        HRS[i] = hn;
    }
    __syncthreads();
    for (int i = tid; i < 1024; i += 256) {
        int c = i >> 4, r = i & 15;
        float hn = HRS[r * 64 + c];
        size_t gi = (size_t)b * 32768 + (size_t)c * 512 + n0 + r;
        ushort hi = f2bf(hn);
        hTh[gi] = hi;
        hTl[gi] = f2bf(hn - bf2f(hi));
    }
}

// ---------------- projections ----------------
__global__ __launch_bounds__(256) void k_proj(
        const float* __restrict__ h, const float* __restrict__ W1cat,
        const float* __restrict__ b1,
        float* __restrict__ sproj, float* __restrict__ tproj) {
    __shared__ float As[16][33];
    __shared__ float Ws[16 * 128];
    int tid = threadIdx.x;
    int row0 = blockIdx.x * 32;
    const float* hp = h + (size_t)row0 * 64;
    float acc[2][8] = {};
    int tx = tid & 15, ty = tid >> 4;
    int lr = tid >> 3;
    int lk = (tid & 7) * 2;
    int wk = tid >> 4;
    int wc = (tid & 15) * 8;
    for (int kt = 0; kt < 4; kt++) {
        int c0 = kt * 16;
        float2 a2 = *(const float2*)&hp[lr * 64 + c0 + lk];
        const float4* wsrc = (const float4*)&W1cat[(size_t)(kt * 16 + wk) * 128 + wc];
        float4 w0 = wsrc[0], w1 = wsrc[1];
        As[lk][lr] = a2.x;
        As[lk + 1][lr] = a2.y;
        *(float4*)&Ws[wk * 128 + wc] = w0;
        *(float4*)&Ws[wk * 128 + wc + 4] = w1;
        __syncthreads();
#pragma unroll
        for (int kk = 0; kk < 16; kk++) {
            float a0 = As[kk][ty * 2 + 0];
            float a1 = As[kk][ty * 2 + 1];
            float4 p0 = *(const float4*)&Ws[kk * 128 + tx * 8];
            float4 p1 = *(const float4*)&Ws[kk * 128 + tx * 8 + 4];
            float w[8] = { p0.x, p0.y, p0.z, p0.w, p1.x, p1.y, p1.z, p1.w };
#pragma unroll
            for (int cc = 0; cc < 8; cc++) {
                acc[0][cc] += a0 * w[cc];
                acc[1][cc] += a1 * w[cc];
            }
        }
        __syncthreads();
    }
#pragma unroll
    for (int rr = 0; rr < 2; rr++) {
        int row = row0 + ty * 2 + rr;
#pragma unroll
        for (int cc = 0; cc < 8; cc++) {
            int col = tx * 8 + cc;
            float v = acc[rr][cc];
            if (col < 64) sproj[(size_t)row * 64 + col] = v + b1[col];
            else tproj[(size_t)row * 64 + (col - 64)] = v;
        }
    }
}

// ---------------- logits ----------------
__global__ __launch_bounds__(256) void k_logits(
        const float* __restrict__ sproj, const float* __restrict__ tproj,
        const float* __restrict__ W2, const float* __restrict__ b2,
        float* __restrict__ out) {
    __shared__ float sp[32 * 64];
    __shared__ float tp[64 * 65];
    __shared__ float w2s[64];
    int tid = threadIdx.x;
    int bb = blockIdx.x >> 7;
    int st = (blockIdx.x >> 3) & 15;
    int tt = blockIdx.x & 7;
    const float* spg = sproj + ((size_t)bb * Nn + st * 32) * 64;
    const float* tpg = tproj + ((size_t)bb * Nn + tt * 64) * 64;
    for (int i = tid; i < 2048; i += 256) sp[i] = spg[i];
    for (int i = tid; i < 4096; i += 256) {
        int tl = i >> 6, hh = i & 63;
        tp[tl * 65 + hh] = tpg[i];
    }
    if (tid < 64) w2s[tid] = W2[tid];
    __syncthreads();
    float bias = *b2;
    int tl = tid & 63, sg = tid >> 6;
    for (int si = 0; si < 8; si++) {
        int s = sg * 8 + si;
        float acc = bias;
#pragma unroll 8
        for (int hh = 0; hh < 64; hh++) {
            float v = sp[s * 64 + hh] + tp[tl * 65 + hh];
            acc += fmaxf(v, 0.f) * w2s[hh];
        }
        out[(size_t)bb * Nn * Nn + (size_t)(st * 32 + s) * Nn + tt * 64 + tl] = acc;
    }
}

// ---------------- host ----------------
extern "C" void kernel_launch(void* const* d_in, const int* in_sizes, int n_in,
                              void* d_out, int out_size, void* d_ws, size_t ws_size,
                              hipStream_t stream) {
    const float* x  = (const float*)d_in[0];
    const float* ew = (const float*)d_in[1];
    const float* Wx = (const float*)d_in[2];
    const float* bx = (const float*)d_in[3];
    const float* Wh = (const float*)d_in[4];
    const float* bh = (const float*)d_in[5];
    const float* W1 = (const float*)d_in[6];
    const float* b1 = (const float*)d_in[7];
    const float* W2 = (const float*)d_in[8];
    const float* b2 = (const float*)d_in[9];
    const int* ei   = (const int*)d_in[10];
    const int* esrc = ei;
    const int* edst = ei + En;

    float* ws = (float*)d_ws;
    float* deg   = ws + OFF_DEG;
    float* dinv  = ws + OFF_DINV;
    float* L1d   = ws + OFF_L1D;
    float* L2d   = ws + OFF_L2D;
    float* WzrC  = ws + OFF_WZR;
    float* WhC   = ws + OFF_WHT;
    float* bzr   = ws + OFF_BZR;
    float* bht   = ws + OFF_BHT;
    float* W1cat = ws + OFF_W1C;
    float* T1x   = ws + OFF_T1X;
    float* T2x   = ws + OFF_T2X;
    float* h     = ws + OFF_H;
    float* z     = ws + OFF_Z;
    float* hr    = ws + OFF_HR;
    float* sproj = ws + OFF_SP;
    float* tproj = ws + OFF_TP;
    ushort* AfH  = (ushort*)(ws + OFF_LFH);
    ushort* AfL  = (ushort*)(ws + OFF_LFL);
    ushort* hTh  = (ushort*)(ws + OFF_HTH);
    ushort* hTl  = (ushort*)(ws + OFF_HTL);
    ushort* hrTh = (ushort*)(ws + OFF_HRTH);
    ushort* hrTl = (ushort*)(ws + OFF_HRTL);
    // W-fragments alias the sproj region (dead until k_proj, which runs after recurrence)
    ushort* WzFH = (ushort*)(ws + OFF_SP);
    ushort* WzFL = WzFH + 98304;
    ushort* WhFH = WzFL + 98304;
    ushort* WhFL = WhFH + 49152;
    float* out   = (float*)d_out;

    hipMemsetAsync(deg, 0, 512 * sizeof(float), stream);
    hipMemsetAsync(L1d, 0, (size_t)Nn * Nn * sizeof(float), stream);
    hipMemsetAsync(h, 0, (size_t)Bn * NC * sizeof(float), stream);
    hipMemsetAsync(hTh, 0, 262144 * sizeof(ushort), stream);
    hipMemsetAsync(hTl, 0, 262144 * sizeof(ushort), stream);

    k_deg<<<64, 256, 0, stream>>>(ew, esrc, deg);
    k_dinv<<<2, 256, 0, stream>>>(deg, dinv);
    k_nwdense<<<64, 256, 0, stream>>>(ew, esrc, edst, dinv, L1d);
    k_l2<<<64, 256, 0, stream>>>(L1d, L2d);
    k_lfrag<<<2048, 256, 0, stream>>>(L1d, L2d, AfH, AfL);
    k_repack<<<(156032 + 255) / 256, 256, 0, stream>>>(Wx, bx, Wh, bh, W1,
                                                       WzrC, WhC, bzr, bht, W1cat);
    k_wfrag<<<(147456 + 255) / 256, 256, 0, stream>>>(WzrC, WhC, WzFH, WzFL, WhFH, WhFL);

    // T1x/T2x via MFMA (spill-free rewrite)
    k_lxm<<<512, 256, 0, stream>>>(AfH, AfL, x, T1x, T2x);

    for (int t = 0; t < Tn; t++) {
        for (int l = 0; l < Ln; l++) {
            k_cell1<<<256, 256, 0, stream>>>(h, x, T1x, T2x, AfH, AfL, hTh, hTl,
                                             WzFH + (size_t)l * 49152,
                                             WzFL + (size_t)l * 49152,
                                             bzr + l * 128, z, hr, hrTh, hrTl, t);
            k_cell2<<<256, 256, 0, stream>>>(hr, x, T1x, T2x, AfH, AfL, hrTh, hrTl,
                                             WhFH + (size_t)l * 24576,
                                             WhFL + (size_t)l * 24576,
                                             bht + l * 64, z, h, hTh, hTl, t);
        }
    }

    k_proj<<<128, 256, 0, stream>>>(h, W1cat, b1, sproj, tproj);
    k_logits<<<Bn * 16 * 8, 256, 0, stream>>>(sproj, tproj, W2, b2, out);
}

// Round 11
// 864.559 us; speedup vs baseline: 3.7465x; 1.2348x over previous
//
#include <hip/hip_runtime.h>

typedef unsigned short ushort;
typedef __attribute__((ext_vector_type(8))) short short8;
typedef __attribute__((ext_vector_type(4))) float f32x4;

// Problem constants
constexpr int Bn = 8, Tn = 16, Nn = 512, Cn = 64, Hn = 64, En = 16384, Ln = 2;
constexpr int NC = Nn * Cn;           // 32768
constexpr int MROWS = Bn * Nn;        // 4096

// ---------------- workspace layout (in floats) ----------------
constexpr size_t OFF_DEG  = 0;
constexpr size_t OFF_DINV = 512;
constexpr size_t OFF_L1D  = 1024;                         // 512*512
constexpr size_t OFF_L2D  = OFF_L1D + 262144;
constexpr size_t OFF_WZR  = OFF_L2D + 262144;             // 2*384*128
constexpr size_t OFF_WHT  = OFF_WZR + 2*384*128;          // 2*384*64
constexpr size_t OFF_BZR  = OFF_WHT + 2*384*64;
constexpr size_t OFF_BHT  = OFF_BZR + 256;
constexpr size_t OFF_W1C  = OFF_BHT + 128;                // 8192
constexpr size_t OFF_T1X  = OFF_W1C + 8192;               // B*T*N*C
constexpr size_t OFF_T2X  = OFF_T1X + (size_t)Bn*Tn*NC;
constexpr size_t OFF_H    = OFF_T2X + (size_t)Bn*Tn*NC;   // B*N*H
constexpr size_t OFF_Z    = OFF_H   + (size_t)Bn*NC;
constexpr size_t OFF_HR   = OFF_Z   + (size_t)Bn*NC;
constexpr size_t OFF_SP   = OFF_HR  + (size_t)Bn*NC;      // sproj; W-frags alias this
constexpr size_t OFF_TP   = OFF_SP  + (size_t)MROWS*Hn;
constexpr size_t OFF_LFH  = OFF_TP  + (size_t)MROWS*Hn;   // L-frags bf16 hi/lo
constexpr size_t OFF_LFL  = OFF_LFH + 262144;
constexpr size_t OFF_HTH  = OFF_LFL + 262144;             // transposed bf16 h/hr (hi only used)
constexpr size_t OFF_HTL  = OFF_HTH + 131072;             // (unused now)
constexpr size_t OFF_HRTH = OFF_HTL + 131072;
constexpr size_t OFF_HRTL = OFF_HRTH + 131072;            // (unused now)
constexpr size_t OFF_END  = OFF_HRTL + 131072;

__device__ __forceinline__ ushort f2bf(float f) {
    unsigned u = __float_as_uint(f);
    u = u + 0x7FFF + ((u >> 16) & 1);
    return (ushort)(u >> 16);
}
__device__ __forceinline__ float bf2f(ushort h) {
    return __uint_as_float(((unsigned)h) << 16);
}
// fragment-linear LDS layout for a 16x64 bf16 A-operand panel:
// value (m,k) lives at (k>>5)*512 + ((k>>3)&3)*128 + m*8 + (k&7)
__device__ __forceinline__ int fragaddr(int m, int k) {
    return ((k >> 5) << 9) + (((k >> 3) & 3) << 7) + (m << 3) + (k & 7);
}

#define MFMA16(a, b, c) __builtin_amdgcn_mfma_f32_16x16x32_bf16((a), (b), (c), 0, 0, 0)

// ---------------- setup kernels ----------------
__global__ void k_deg(const float* __restrict__ w, const int* __restrict__ src,
                      float* __restrict__ deg) {
    int e = blockIdx.x * 256 + threadIdx.x;
    if (e < En) atomicAdd(&deg[src[e]], w[e]);
}

__global__ void k_dinv(const float* __restrict__ deg, float* __restrict__ dinv) {
    int n = blockIdx.x * 256 + threadIdx.x;
    if (n < Nn) {
        float d = deg[n];
        dinv[n] = d > 0.f ? rsqrtf(fmaxf(d, 1e-12f)) : 0.f;
    }
}

__global__ void k_nwdense(const float* __restrict__ w, const int* __restrict__ src,
                          const int* __restrict__ dst, const float* __restrict__ dinv,
                          float* __restrict__ L1d) {
    int e = blockIdx.x * 256 + threadIdx.x;
    if (e < En) {
        int s = src[e], d = dst[e];
        float nw = -w[e] * dinv[s] * dinv[d];
        atomicAdd(&L1d[d * Nn + s], nw);
    }
}

// L2 = 2*(L1@L1) - I
__global__ __launch_bounds__(256) void k_l2(const float* __restrict__ A,
                                            float* __restrict__ C) {
    __shared__ float As[64][33];
    __shared__ float Bs[32][65];
    int t = threadIdx.x;
    int i0 = (blockIdx.x >> 3) * 64;
    int j0 = (blockIdx.x & 7) * 64;
    int tx = t & 15, ty = t >> 4;
    float acc[4][4] = {};
    int ar = t >> 2, ac = (t & 3) * 8;
    int br = t >> 3, bc = (t & 7) * 8;
    for (int kc = 0; kc < 512; kc += 32) {
        float4 a0 = *(const float4*)&A[(size_t)(i0 + ar) * 512 + kc + ac];
        float4 a1 = *(const float4*)&A[(size_t)(i0 + ar) * 512 + kc + ac + 4];
        float4 b0 = *(const float4*)&A[(size_t)(kc + br) * 512 + j0 + bc];
        float4 b1 = *(const float4*)&A[(size_t)(kc + br) * 512 + j0 + bc + 4];
        As[ar][ac+0]=a0.x; As[ar][ac+1]=a0.y; As[ar][ac+2]=a0.z; As[ar][ac+3]=a0.w;
        As[ar][ac+4]=a1.x; As[ar][ac+5]=a1.y; As[ar][ac+6]=a1.z; As[ar][ac+7]=a1.w;
        Bs[br][bc+0]=b0.x; Bs[br][bc+1]=b0.y; Bs[br][bc+2]=b0.z; Bs[br][bc+3]=b0.w;
        Bs[br][bc+4]=b1.x; Bs[br][bc+5]=b1.y; Bs[br][bc+6]=b1.z; Bs[br][bc+7]=b1.w;
        __syncthreads();
#pragma unroll 8
        for (int kk = 0; kk < 32; kk++) {
            float av[4], bv[4];
#pragma unroll
            for (int r = 0; r < 4; r++) av[r] = As[ty * 4 + r][kk];
#pragma unroll
            for (int c = 0; c < 4; c++) bv[c] = Bs[kk][tx * 4 + c];
#pragma unroll
            for (int r = 0; r < 4; r++)
#pragma unroll
                for (int c = 0; c < 4; c++) acc[r][c] += av[r] * bv[c];
        }
        __syncthreads();
    }
#pragma unroll
    for (int r = 0; r < 4; r++)
#pragma unroll
        for (int c = 0; c < 4; c++) {
            int i = i0 + ty * 4 + r, j = j0 + tx * 4 + c;
            C[(size_t)i * 512 + j] = 2.f * acc[r][c] - (i == j ? 1.f : 0.f);
        }
}

// L1/L2 -> bf16 split A-fragments; idx = ((mat*32+rb)*16 + kc)*512 + lane*8 + j
__global__ void k_lfrag(const float* __restrict__ L1, const float* __restrict__ L2,
                        ushort* __restrict__ AfH, ushort* __restrict__ AfL) {
    int idx = blockIdx.x * 256 + threadIdx.x;   // 0..524287
    int j = idx & 7;
    int lane = (idx >> 3) & 63;
    int kc = (idx >> 9) & 15;
    int rb = (idx >> 13) & 31;
    int mat = idx >> 18;
    int row = rb * 16 + (lane & 15);
    int k = kc * 32 + (lane >> 4) * 8 + j;
    float v = (mat ? L2 : L1)[(size_t)row * 512 + k];
    ushort hi = f2bf(v);
    AfH[idx] = hi;
    AfL[idx] = f2bf(v - bf2f(hi));
}

// Wzr/Wht -> bf16 split B-fragments: idx = ((l*CT + ct)*12 + kc)*512 + lane*8 + j
__global__ void k_wfrag(const float* __restrict__ WzrC, const float* __restrict__ WhC,
                        ushort* __restrict__ WzFH, ushort* __restrict__ WzFL,
                        ushort* __restrict__ WhFH, ushort* __restrict__ WhFL) {
    int idx = blockIdx.x * 256 + threadIdx.x;
    if (idx < 98304) {
        int l = idx / 49152, off = idx % 49152;
        int tile = off >> 9, r = off & 511;
        int lane = r >> 3, j = r & 7;
        int ct = tile / 12, kc = tile % 12;
        int k = kc * 32 + (lane >> 4) * 8 + j;
        int n = ct * 16 + (lane & 15);
        float v = WzrC[(size_t)l * 49152 + k * 128 + n];
        ushort hi = f2bf(v);
        WzFH[idx] = hi;
        WzFL[idx] = f2bf(v - bf2f(hi));
    } else if (idx < 147456) {
        int t2 = idx - 98304;
        int l = t2 / 24576, off = t2 % 24576;
        int tile = off >> 9, r = off & 511;
        int lane = r >> 3, j = r & 7;
        int ct = tile / 12, kc = tile % 12;
        int k = kc * 32 + (lane >> 4) * 8 + j;
        int n = ct * 16 + (lane & 15);
        float v = WhC[(size_t)l * 24576 + k * 64 + n];
        ushort hi = f2bf(v);
        WhFH[t2] = hi;
        WhFL[t2] = f2bf(v - bf2f(hi));
    }
}

// ---------------- MFMA T1x/T2x: o1 = L1@x, o2 = L2@x per slice ----------------
// 1024 blocks = 128 slices x 8 rowgroups; 1 row-tile per wave -> 4 waves/SIMD.
__global__ __launch_bounds__(256) void k_lxm(
        const ushort* __restrict__ AfH, const ushort* __restrict__ AfL,
        const float* __restrict__ in, float* __restrict__ o1, float* __restrict__ o2) {
    __shared__ ushort Bh[2][2176];   // [buf][n*34 + k] (pad 34 halves)
    __shared__ ushort Bl[2][2176];
    int slice = blockIdx.x >> 3;
    int rg = blockIdx.x & 7;
    const float* xs = in + (size_t)slice * NC;
    int tid = threadIdx.x;
    int lane = tid & 63, wav = tid >> 6;
    int quad = lane >> 4, l15 = lane & 15;
    int sn = tid & 63, skq = tid >> 6;
    int rt = rg * 4 + wav;
    size_t abA = ((size_t)rt * 16) * 512 + lane * 8;        // L1 rows
    size_t abB = ((size_t)(32 + rt) * 16) * 512 + lane * 8; // L2 rows
    f32x4 accA[4], accB[4];
#pragma unroll
    for (int n = 0; n < 4; n++) {
        accA[n] = (f32x4){0.f, 0.f, 0.f, 0.f};
        accB[n] = (f32x4){0.f, 0.f, 0.f, 0.f};
    }
    // stage chunk 0 into buf 0
    {
        short8 hi8, lo8;
#pragma unroll
        for (int i = 0; i < 8; i++) {
            float v = xs[(size_t)(skq * 8 + i) * 64 + sn];
            ushort hv = f2bf(v);
            hi8[i] = (short)hv;
            lo8[i] = (short)f2bf(v - bf2f(hv));
        }
        *(short8*)&Bh[0][sn * 34 + skq * 8] = hi8;
        *(short8*)&Bl[0][sn * 34 + skq * 8] = lo8;
    }
    __syncthreads();
#pragma unroll
    for (int kc = 0; kc < 16; kc++) {
        const int cur = kc & 1;
        float sv[8];
        if (kc < 15) {
#pragma unroll
            for (int i = 0; i < 8; i++)
                sv[i] = xs[(size_t)((kc + 1) * 32 + skq * 8 + i) * 64 + sn];
        }
        size_t o = (size_t)kc * 512;
        short8 lah = *(const short8*)&AfH[abA + o];
        short8 lal = *(const short8*)&AfL[abA + o];
        short8 lbh = *(const short8*)&AfH[abB + o];
        short8 lbl = *(const short8*)&AfL[abB + o];
#pragma unroll
        for (int nt = 0; nt < 4; nt++) {
            short8 xh = *(const short8*)&Bh[cur][(nt * 16 + l15) * 34 + quad * 8];
            short8 xl = *(const short8*)&Bl[cur][(nt * 16 + l15) * 34 + quad * 8];
            accA[nt] = MFMA16(lah, xh, accA[nt]);
            accA[nt] = MFMA16(lah, xl, accA[nt]);
            accA[nt] = MFMA16(lal, xh, accA[nt]);
            accB[nt] = MFMA16(lbh, xh, accB[nt]);
            accB[nt] = MFMA16(lbh, xl, accB[nt]);
            accB[nt] = MFMA16(lbl, xh, accB[nt]);
        }
        if (kc < 15) {
            short8 hi8, lo8;
#pragma unroll
            for (int i = 0; i < 8; i++) {
                ushort hv = f2bf(sv[i]);
                hi8[i] = (short)hv;
                lo8[i] = (short)f2bf(sv[i] - bf2f(hv));
            }
            *(short8*)&Bh[cur ^ 1][sn * 34 + skq * 8] = hi8;
            *(short8*)&Bl[cur ^ 1][sn * 34 + skq * 8] = lo8;
        }
        __syncthreads();
    }
    float* os1 = o1 + (size_t)slice * NC;
    float* os2 = o2 + (size_t)slice * NC;
#pragma unroll
    for (int nt = 0; nt < 4; nt++)
#pragma unroll
        for (int reg = 0; reg < 4; reg++) {
            size_t row = (size_t)(rt * 16 + quad * 4 + reg);
            os1[row * 64 + nt * 16 + l15] = accA[nt][reg];
            os2[row * 64 + nt * 16 + l15] = accB[nt][reg];
        }
}

// repack weights
__global__ void k_repack(const float* __restrict__ Wx, const float* __restrict__ bx,
                         const float* __restrict__ Wh, const float* __restrict__ bh,
                         const float* __restrict__ W1,
                         float* __restrict__ WzrC, float* __restrict__ WhC,
                         float* __restrict__ bzr, float* __restrict__ bht,
                         float* __restrict__ W1cat) {
    int idx = blockIdx.x * 256 + threadIdx.x;
    if (idx < 98304) {
        int l = idx / 49152, r = idx % 49152;
        int k = r / 128, j = r % 128;
        int g = j >> 6, hh = j & 63;
        int kc, c; const float* s;
        if (k < 192) { kc = k / 64; c = k % 64; s = Wh; }
        else { kc = (k - 192) / 64; c = (k - 192) % 64; s = Wx; }
        WzrC[idx] = s[((((size_t)(l*3 + g))*3 + kc)*64 + c)*64 + hh];
    } else if (idx < 147456) {
        int tI = idx - 98304;
        int l = tI / 24576, r = tI % 24576;
        int k = r / 64, hh = r % 64;
        int kc, c; const float* s;
        if (k < 192) { kc = k / 64; c = k % 64; s = Wh; }
        else { kc = (k - 192) / 64; c = (k - 192) % 64; s = Wx; }
        WhC[tI] = s[((((size_t)(l*3 + 2))*3 + kc)*64 + c)*64 + hh];
    } else if (idx < 147712) {
        int tI = idx - 147456;
        int l = tI >> 7, j = tI & 127;
        int g = j >> 6, hh = j & 63;
        bzr[tI] = bh[(l*3 + g)*64 + hh] + bx[(l*3 + g)*64 + hh];
    } else if (idx < 147840) {
        int tI = idx - 147712;
        int l = tI >> 6, hh = tI & 63;
        bht[tI] = bh[(l*3 + 2)*64 + hh] + bx[(l*3 + 2)*64 + hh];
    } else if (idx < 156032) {
        int tI = idx - 147840;
        int c = tI >> 7, j = tI & 127;
        W1cat[tI] = (j < 64) ? W1[c*64 + j] : W1[(64 + c)*64 + (j - 64)];
    }
}

// ================= full-MFMA cell kernels: 256 blocks x 16 rows =================
// LDS (floats): AH@0 (3072) | AL@3072 (3072) | PRED@6144 (2048) | HRS@8192 (1024)

// common: stage segs 0,3,4,5 (fp32 global -> bf16 hi/lo frags)
__device__ __forceinline__ void stage_segs(
        ushort* AH, ushort* AL, const float* s0, const float* x,
        const float* t1x, const float* t2x, size_t xoff, int tid) {
    int p = tid * 4;
    int m = p >> 6, kb = p & 63;
    int fa = fragaddr(m, kb);
    const float* srcs[4] = { s0, x + xoff, t1x + xoff, t2x + xoff };
    const int sidx[4] = { 0, 3, 4, 5 };
#pragma unroll
    for (int q = 0; q < 4; q++) {
        float4 v = *(const float4*)&srcs[q][(size_t)m * 64 + kb];
        float vv[4] = { v.x, v.y, v.z, v.w };
        int base = sidx[q] * 1024 + fa;
#pragma unroll
        for (int j = 0; j < 4; j++) {
            ushort hi = f2bf(vv[j]);
            AH[base + j] = hi;
            AL[base + j] = f2bf(vv[j] - bf2f(hi));
        }
    }
}

// phase A: U1 = L1[rows,:]@src, U2 = L2[rows,:]@src via split-bf16 MFMA.
// B-side (transposed h/hr) is HI ONLY (lo dropped: error ~|h|*2^-9, under budget);
// A-side (L) keeps full hi/lo split. 4 MFMAs per kc (was 6), half the B traffic.
__device__ __forceinline__ void phase_A16(
        ushort* AH, ushort* AL,
        const ushort* __restrict__ sTh,
        const ushort* __restrict__ AfH, const ushort* __restrict__ AfL,
        int rowblk, int tid) {
    int lane = tid & 63, wav = tid >> 6;
    int quad = lane >> 4, l15 = lane & 15;
    size_t ab1 = ((size_t)rowblk * 16) * 512 + lane * 8;
    size_t ab2 = ((size_t)(32 + rowblk) * 16) * 512 + lane * 8;
    size_t bb = (size_t)(wav * 16 + l15) * 512 + quad * 8;
    f32x4 p1a = {0.f,0.f,0.f,0.f}, p1c = p1a;
    f32x4 p2a = p1a, p2c = p1a;
    short8 a1h[4], a1l[4], a2h[4], a2l[4], bh[4];
#pragma unroll
    for (int s = 0; s < 4; s++) {
        size_t o = (size_t)s * 512;
        a1h[s] = *(const short8*)&AfH[ab1 + o];
        a1l[s] = *(const short8*)&AfL[ab1 + o];
        a2h[s] = *(const short8*)&AfH[ab2 + o];
        a2l[s] = *(const short8*)&AfL[ab2 + o];
        bh[s]  = *(const short8*)&sTh[bb + s * 32];
    }
#pragma unroll
    for (int kc = 0; kc < 16; kc++) {
        int s = kc & 3;
        p1a = MFMA16(a1h[s], bh[s], p1a);
        p1c = MFMA16(a1l[s], bh[s], p1c);
        p2a = MFMA16(a2h[s], bh[s], p2a);
        p2c = MFMA16(a2l[s], bh[s], p2c);
        if (kc + 4 < 16) {
            size_t o = (size_t)(kc + 4) * 512;
            a1h[s] = *(const short8*)&AfH[ab1 + o];
            a1l[s] = *(const short8*)&AfL[ab1 + o];
            a2h[s] = *(const short8*)&AfH[ab2 + o];
            a2l[s] = *(const short8*)&AfL[ab2 + o];
            bh[s]  = *(const short8*)&sTh[bb + (kc + 4) * 32];
        }
    }
    int colA = wav * 16 + l15;
#pragma unroll
    for (int reg = 0; reg < 4; reg++) {
        int row = quad * 4 + reg;
        float u1 = p1a[reg] + p1c[reg];
        float u2 = p2a[reg] + p2c[reg];
        ushort h1 = f2bf(u1), h2 = f2bf(u2);
        int fa1 = 1024 + fragaddr(row, colA);
        int fa2 = 2048 + fragaddr(row, colA);
        AH[fa1] = h1; AL[fa1] = f2bf(u1 - bf2f(h1));
        AH[fa2] = h2; AL[fa2] = f2bf(u2 - bf2f(h2));
    }
}

// stage1: z,r = sigmoid(A@Wzr + b); z->global; hr = h*r -> global fp32 + bf16-hi transposed
__global__ __launch_bounds__(256) void k_cell1(
        const float* __restrict__ h, const float* __restrict__ x,
        const float* __restrict__ t1x, const float* __restrict__ t2x,
        const ushort* __restrict__ AfH, const ushort* __restrict__ AfL,
        const ushort* __restrict__ hTh,
        const ushort* __restrict__ WFH, const ushort* __restrict__ WFL,
        const float* __restrict__ bias,
        float* __restrict__ z, float* __restrict__ hr,
        ushort* __restrict__ hrTh, int t) {
    __shared__ float lds[9216];
    ushort* AH = (ushort*)lds;
    ushort* AL = (ushort*)(lds + 3072);
    float* PRED = lds + 6144;
    float* HRS  = lds + 8192;
    int tid = threadIdx.x;
    int b = blockIdx.x >> 5;
    int rowblk = blockIdx.x & 31;
    int n0 = rowblk * 16;
    size_t hoff = ((size_t)b * Nn + n0) * 64;
    size_t xoff = ((size_t)(b * Tn + t) * Nn + n0) * 64;

    stage_segs(AH, AL, h + hoff, x, t1x, t2x, xoff, tid);
    phase_A16(AH, AL, hTh + (size_t)b * 32768, AfH, AfL, rowblk, tid);
    __syncthreads();

    // phase B1: zr[16][128] = A[16][384] @ Wzr — depth-4 W / depth-2 A, split accs
    int lane = tid & 63, wav = tid >> 6;
    int quad = lane >> 4, l15 = lane & 15;
    {
        int abase = quad * 128 + l15 * 8;
        size_t w0 = ((size_t)wav * 12) * 512 + lane * 8;
        size_t w1 = ((size_t)(4 + wav) * 12) * 512 + lane * 8;
        f32x4 q0a = {0.f,0.f,0.f,0.f}, q0b = q0a, q0c = q0a;
        f32x4 q1a = q0a, q1b = q0a, q1c = q0a;
        short8 ah[2], al[2], w0h[4], w0l[4], w1h[4], w1l[4];
#pragma unroll
        for (int s = 0; s < 2; s++) {
            ah[s] = *(const short8*)&AH[abase + s * 512];
            al[s] = *(const short8*)&AL[abase + s * 512];
        }
#pragma unroll
        for (int s = 0; s < 4; s++) {
            size_t o = (size_t)s * 512;
            w0h[s] = *(const short8*)&WFH[w0 + o];
            w0l[s] = *(const short8*)&WFL[w0 + o];
            w1h[s] = *(const short8*)&WFH[w1 + o];
            w1l[s] = *(const short8*)&WFL[w1 + o];
        }
#pragma unroll
        for (int kt = 0; kt < 12; kt++) {
            int sa = kt & 1, sw = kt & 3;
            q0a = MFMA16(ah[sa], w0h[sw], q0a);
            q0b = MFMA16(ah[sa], w0l[sw], q0b);
            q0c = MFMA16(al[sa], w0h[sw], q0c);
            q1a = MFMA16(ah[sa], w1h[sw], q1a);
            q1b = MFMA16(ah[sa], w1l[sw], q1b);
            q1c = MFMA16(al[sa], w1h[sw], q1c);
            if (kt + 2 < 12) {
                ah[sa] = *(const short8*)&AH[abase + (kt + 2) * 512];
                al[sa] = *(const short8*)&AL[abase + (kt + 2) * 512];
            }
            if (kt + 4 < 12) {
                size_t o = (size_t)(kt + 4) * 512;
                w0h[sw] = *(const short8*)&WFH[w0 + o];
                w0l[sw] = *(const short8*)&WFL[w0 + o];
                w1h[sw] = *(const short8*)&WFH[w1 + o];
                w1l[sw] = *(const short8*)&WFL[w1 + o];
            }
        }
#pragma unroll
        for (int reg = 0; reg < 4; reg++) {
            int row = quad * 4 + reg;
            PRED[row * 128 + wav * 16 + l15] = q0a[reg] + q0b[reg] + q0c[reg];
            PRED[row * 128 + 64 + wav * 16 + l15] = q1a[reg] + q1b[reg] + q1c[reg];
        }
    }
    __syncthreads();
    for (int i = tid; i < 2048; i += 256) {
        int r = i >> 7, c = i & 127;
        float v = PRED[i] + bias[c];
        float s = 1.f / (1.f + __expf(-v));
        size_t grow = ((size_t)(b * Nn + n0 + r)) * 64;
        if (c < 64) {
            z[grow + c] = s;
        } else {
            int c2 = c - 64;
            int fa = fragaddr(r, c2);
            float hv = bf2f(AH[fa]) + bf2f(AL[fa]);
            float hrv = hv * s;
            hr[grow + c2] = hrv;
            HRS[r * 64 + c2] = hrv;
        }
    }
    __syncthreads();
    for (int i = tid; i < 1024; i += 256) {
        int c = i >> 4, r = i & 15;
        size_t gi = (size_t)b * 32768 + (size_t)c * 512 + n0 + r;
        hrTh[gi] = f2bf(HRS[r * 64 + c]);
    }
}

// stage2: ht = tanh(A@Wht + b); h = z*h + (1-z)*ht -> global fp32 + bf16-hi transposed
__global__ __launch_bounds__(256) void k_cell2(
        const float* __restrict__ hrp, const float* __restrict__ x,
        const float* __restrict__ t1x, const float* __restrict__ t2x,
        const ushort* __restrict__ AfH, const ushort* __restrict__ AfL,
        const ushort* __restrict__ hrTh,
        const ushort* __restrict__ WFH, const ushort* __restrict__ WFL,
        const float* __restrict__ bias,
        const float* __restrict__ z, float* __restrict__ h,
        ushort* __restrict__ hTh, int t) {
    __shared__ float lds[9216];
    ushort* AH = (ushort*)lds;
    ushort* AL = (ushort*)(lds + 3072);
    float* PRED = lds + 6144;
    float* HRS  = lds + 8192;
    int tid = threadIdx.x;
    int b = blockIdx.x >> 5;
    int rowblk = blockIdx.x & 31;
    int n0 = rowblk * 16;
    size_t hoff = ((size_t)b * Nn + n0) * 64;
    size_t xoff = ((size_t)(b * Tn + t) * Nn + n0) * 64;

    stage_segs(AH, AL, hrp + hoff, x, t1x, t2x, xoff, tid);
    phase_A16(AH, AL, hrTh + (size_t)b * 32768, AfH, AfL, rowblk, tid);
    __syncthreads();

    // phase B2: ht[16][64] = A[16][384] @ Wht — depth-4 W / depth-2 A, split accs
    int lane = tid & 63, wav = tid >> 6;
    int quad = lane >> 4, l15 = lane & 15;
    {
        int abase = quad * 128 + l15 * 8;
        size_t w0 = ((size_t)wav * 12) * 512 + lane * 8;
        f32x4 qa = {0.f,0.f,0.f,0.f}, qb = qa, qc = qa;
        short8 ah[2], al[2], wh[4], wl[4];
#pragma unroll
        for (int s = 0; s < 2; s++) {
            ah[s] = *(const short8*)&AH[abase + s * 512];
            al[s] = *(const short8*)&AL[abase + s * 512];
        }
#pragma unroll
        for (int s = 0; s < 4; s++) {
            wh[s] = *(const short8*)&WFH[w0 + (size_t)s * 512];
            wl[s] = *(const short8*)&WFL[w0 + (size_t)s * 512];
        }
#pragma unroll
        for (int kt = 0; kt < 12; kt++) {
            int sa = kt & 1, sw = kt & 3;
            qa = MFMA16(ah[sa], wh[sw], qa);
            qb = MFMA16(ah[sa], wl[sw], qb);
            qc = MFMA16(al[sa], wh[sw], qc);
            if (kt + 2 < 12) {
                ah[sa] = *(const short8*)&AH[abase + (kt + 2) * 512];
                al[sa] = *(const short8*)&AL[abase + (kt + 2) * 512];
            }
            if (kt + 4 < 12) {
                size_t o = (size_t)(kt + 4) * 512;
                wh[sw] = *(const short8*)&WFH[w0 + o];
                wl[sw] = *(const short8*)&WFL[w0 + o];
            }
        }
#pragma unroll
        for (int reg = 0; reg < 4; reg++)
            PRED[(quad * 4 + reg) * 64 + wav * 16 + l15] = qa[reg] + qb[reg] + qc[reg];
    }
    __syncthreads();
    for (int i = tid; i < 1024; i += 256) {
        int c = i & 63;
        float v = PRED[i] + bias[c];
        // fast tanh (NaN-safe): tanh(v) = sign(v) * (1-e^{-2|v|})/(1+e^{-2|v|})
        float av = fabsf(v);
        float e2 = __expf(-2.f * av);
        float m = (1.f - e2) / (1.f + e2);
        float ht = v < 0.f ? -m : m;
        size_t p = ((size_t)(b * Nn + n0 + (i >> 6))) * 64 + c;
        float zz = z[p], hold = h[p];
        float hn = zz * hold + (1.f - zz) * ht;
        h[p] = hn;
        HRS[i] = hn;
    }
    __syncthreads();
    for (int i = tid; i < 1024; i += 256) {
        int c = i >> 4, r = i & 15;
        size_t gi = (size_t)b * 32768 + (size_t)c * 512 + n0 + r;
        hTh[gi] = f2bf(HRS[r * 64 + c]);
    }
}

// ---------------- projections ----------------
__global__ __launch_bounds__(256) void k_proj(
        const float* __restrict__ h, const float* __restrict__ W1cat,
        const float* __restrict__ b1,
        float* __restrict__ sproj, float* __restrict__ tproj) {
    __shared__ float As[16][33];
    __shared__ float Ws[16 * 128];
    int tid = threadIdx.x;
    int row0 = blockIdx.x * 32;
    const float* hp = h + (size_t)row0 * 64;
    float acc[2][8] = {};
    int tx = tid & 15, ty = tid >> 4;
    int lr = tid >> 3;
    int lk = (tid & 7) * 2;
    int wk = tid >> 4;
    int wc = (tid & 15) * 8;
    for (int kt = 0; kt < 4; kt++) {
        int c0 = kt * 16;
        float2 a2 = *(const float2*)&hp[lr * 64 + c0 + lk];
        const float4* wsrc = (const float4*)&W1cat[(size_t)(kt * 16 + wk) * 128 + wc];
        float4 w0 = wsrc[0], w1 = wsrc[1];
        As[lk][lr] = a2.x;
        As[lk + 1][lr] = a2.y;
        *(float4*)&Ws[wk * 128 + wc] = w0;
        *(float4*)&Ws[wk * 128 + wc + 4] = w1;
        __syncthreads();
#pragma unroll
        for (int kk = 0; kk < 16; kk++) {
            float a0 = As[kk][ty * 2 + 0];
            float a1 = As[kk][ty * 2 + 1];
            float4 p0 = *(const float4*)&Ws[kk * 128 + tx * 8];
            float4 p1 = *(const float4*)&Ws[kk * 128 + tx * 8 + 4];
            float w[8] = { p0.x, p0.y, p0.z, p0.w, p1.x, p1.y, p1.z, p1.w };
#pragma unroll
            for (int cc = 0; cc < 8; cc++) {
                acc[0][cc] += a0 * w[cc];
                acc[1][cc] += a1 * w[cc];
            }
        }
        __syncthreads();
    }
#pragma unroll
    for (int rr = 0; rr < 2; rr++) {
        int row = row0 + ty * 2 + rr;
#pragma unroll
        for (int cc = 0; cc < 8; cc++) {
            int col = tx * 8 + cc;
            float v = acc[rr][cc];
            if (col < 64) sproj[(size_t)row * 64 + col] = v + b1[col];
            else tproj[(size_t)row * 64 + (col - 64)] = v;
        }
    }
}

// ---------------- logits ----------------
__global__ __launch_bounds__(256) void k_logits(
        const float* __restrict__ sproj, const float* __restrict__ tproj,
        const float* __restrict__ W2, const float* __restrict__ b2,
        float* __restrict__ out) {
    __shared__ float sp[32 * 64];
    __shared__ float tp[64 * 65];
    __shared__ float w2s[64];
    int tid = threadIdx.x;
    int bb = blockIdx.x >> 7;
    int st = (blockIdx.x >> 3) & 15;
    int tt = blockIdx.x & 7;
    const float* spg = sproj + ((size_t)bb * Nn + st * 32) * 64;
    const float* tpg = tproj + ((size_t)bb * Nn + tt * 64) * 64;
    for (int i = tid; i < 2048; i += 256) sp[i] = spg[i];
    for (int i = tid; i < 4096; i += 256) {
        int tl = i >> 6, hh = i & 63;
        tp[tl * 65 + hh] = tpg[i];
    }
    if (tid < 64) w2s[tid] = W2[tid];
    __syncthreads();
    float bias = *b2;
    int tl = tid & 63, sg = tid >> 6;
    for (int si = 0; si < 8; si++) {
        int s = sg * 8 + si;
        float acc = bias;
#pragma unroll 8
        for (int hh = 0; hh < 64; hh++) {
            float v = sp[s * 64 + hh] + tp[tl * 65 + hh];
            acc += fmaxf(v, 0.f) * w2s[hh];
        }
        out[(size_t)bb * Nn * Nn + (size_t)(st * 32 + s) * Nn + tt * 64 + tl] = acc;
    }
}

// ---------------- host ----------------
extern "C" void kernel_launch(void* const* d_in, const int* in_sizes, int n_in,
                              void* d_out, int out_size, void* d_ws, size_t ws_size,
                              hipStream_t stream) {
    const float* x  = (const float*)d_in[0];
    const float* ew = (const float*)d_in[1];
    const float* Wx = (const float*)d_in[2];
    const float* bx = (const float*)d_in[3];
    const float* Wh = (const float*)d_in[4];
    const float* bh = (const float*)d_in[5];
    const float* W1 = (const float*)d_in[6];
    const float* b1 = (const float*)d_in[7];
    const float* W2 = (const float*)d_in[8];
    const float* b2 = (const float*)d_in[9];
    const int* ei   = (const int*)d_in[10];
    const int* esrc = ei;
    const int* edst = ei + En;

    float* ws = (float*)d_ws;
    float* deg   = ws + OFF_DEG;
    float* dinv  = ws + OFF_DINV;
    float* L1d   = ws + OFF_L1D;
    float* L2d   = ws + OFF_L2D;
    float* WzrC  = ws + OFF_WZR;
    float* WhC   = ws + OFF_WHT;
    float* bzr   = ws + OFF_BZR;
    float* bht   = ws + OFF_BHT;
    float* W1cat = ws + OFF_W1C;
    float* T1x   = ws + OFF_T1X;
    float* T2x   = ws + OFF_T2X;
    float* h     = ws + OFF_H;
    float* z     = ws + OFF_Z;
    float* hr    = ws + OFF_HR;
    float* sproj = ws + OFF_SP;
    float* tproj = ws + OFF_TP;
    ushort* AfH  = (ushort*)(ws + OFF_LFH);
    ushort* AfL  = (ushort*)(ws + OFF_LFL);
    ushort* hTh  = (ushort*)(ws + OFF_HTH);
    ushort* hrTh = (ushort*)(ws + OFF_HRTH);
    // W-fragments alias the sproj region (dead until k_proj, which runs after recurrence)
    ushort* WzFH = (ushort*)(ws + OFF_SP);
    ushort* WzFL = WzFH + 98304;
    ushort* WhFH = WzFL + 98304;
    ushort* WhFL = WhFH + 49152;
    float* out   = (float*)d_out;

    hipMemsetAsync(deg, 0, 512 * sizeof(float), stream);
    hipMemsetAsync(L1d, 0, (size_t)Nn * Nn * sizeof(float), stream);
    hipMemsetAsync(h, 0, (size_t)Bn * NC * sizeof(float), stream);
    hipMemsetAsync(hTh, 0, 262144 * sizeof(ushort), stream);

    k_deg<<<64, 256, 0, stream>>>(ew, esrc, deg);
    k_dinv<<<2, 256, 0, stream>>>(deg, dinv);
    k_nwdense<<<64, 256, 0, stream>>>(ew, esrc, edst, dinv, L1d);
    k_l2<<<64, 256, 0, stream>>>(L1d, L2d);
    k_lfrag<<<2048, 256, 0, stream>>>(L1d, L2d, AfH, AfL);
    k_repack<<<(156032 + 255) / 256, 256, 0, stream>>>(Wx, bx, Wh, bh, W1,
                                                       WzrC, WhC, bzr, bht, W1cat);
    k_wfrag<<<(147456 + 255) / 256, 256, 0, stream>>>(WzrC, WhC, WzFH, WzFL, WhFH, WhFL);

    // T1x/T2x via MFMA — 1024 blocks (4 waves/SIMD)
    k_lxm<<<1024, 256, 0, stream>>>(AfH, AfL, x, T1x, T2x);

    for (int t = 0; t < Tn; t++) {
        for (int l = 0; l < Ln; l++) {
            k_cell1<<<256, 256, 0, stream>>>(h, x, T1x, T2x, AfH, AfL, hTh,
                                             WzFH + (size_t)l * 49152,
                                             WzFL + (size_t)l * 49152,
                                             bzr + l * 128, z, hr, hrTh, t);
            k_cell2<<<256, 256, 0, stream>>>(hr, x, T1x, T2x, AfH, AfL, hrTh,
                                             WhFH + (size_t)l * 24576,
                                             WhFL + (size_t)l * 24576,
                                             bht + l * 64, z, h, hTh, t);
        }
    }

    k_proj<<<128, 256, 0, stream>>>(h, W1cat, b1, sproj, tproj);
    k_logits<<<Bn * 16 * 8, 256, 0, stream>>>(sproj, tproj, W2, b2, out);
}